// Round 11
// baseline (436.835 us; speedup 1.0000x reference)
//
#include <hip/hip_runtime.h>

#define CKD 512
#define NROWS 44
#define XPLANE 360448  // 16*44*512

static __device__ __forceinline__ int imin(int a, int b) { return a < b ? a : b; }

typedef short bf16x8 __attribute__((ext_vector_type(8)));
typedef float f32x4 __attribute__((ext_vector_type(4)));
typedef unsigned int uint32;

// RNE float->bf16 pack of two floats into one u32 (lo = a, hi = b)
static __device__ __forceinline__ unsigned int pk2(float a, float b) {
  unsigned int ua = __float_as_uint(a), ub = __float_as_uint(b);
  ua = (ua + 0x7fffu + ((ua >> 16) & 1u)) >> 16;
  ub = (ub + 0x7fffu + ((ub >> 16) & 1u)) >> 16;
  return ua | (ub << 16);
}

static __device__ __forceinline__ uint32 ror16(uint32 q) { return (q >> 16) | (q << 16); }

static __device__ __forceinline__ bf16x8 mk_neghi(uint32 q0, uint32 q1, uint32 q2, uint32 q3) {
  union { uint32 u[4]; bf16x8 h; } t;
  t.u[0] = q0 ^ 0x80000000u; t.u[1] = q1 ^ 0x80000000u;
  t.u[2] = q2 ^ 0x80000000u; t.u[3] = q3 ^ 0x80000000u;
  return t.h;
}
static __device__ __forceinline__ bf16x8 mk_swap(uint32 q0, uint32 q1, uint32 q2, uint32 q3) {
  union { uint32 u[4]; bf16x8 h; } t;
  t.u[0] = ror16(q0); t.u[1] = ror16(q1); t.u[2] = ror16(q2); t.u[3] = ror16(q3);
  return t.h;
}

// ---------------------------------------------------------------------------
// Convert x (4,3072,512) fp32 -> Xb (4,4096,512) bf16 with wraparound pad
// ---------------------------------------------------------------------------
__global__ __launch_bounds__(256) void k_cvt_x(
    const float* __restrict__ src, unsigned short* __restrict__ dst)
{
  int g = blockIdx.x * 256 + threadIdx.x;      // 16384*64
  int row = g >> 6, c8 = (g & 63) << 3;
  int b = row >> 12, t = row & 4095;
  if (t >= 3072) t -= 3072;
  const float* s = src + ((size_t)(b * 3072 + t) << 9) + c8;
  float4 v0 = *(const float4*)s;
  float4 v1 = *(const float4*)(s + 4);
  uint4 o = make_uint4(pk2(v0.x, v0.y), pk2(v0.z, v0.w),
                       pk2(v1.x, v1.y), pk2(v1.z, v1.w));
  *(uint4*)(dst + ((size_t)row << 9) + c8) = o;
}

__global__ __launch_bounds__(256) void k_cvt_gen(
    const float* __restrict__ src, unsigned short* __restrict__ dst)
{
  int g = blockIdx.x * 256 + threadIdx.x;
  const float* s = src + ((size_t)g << 3);
  float4 v0 = *(const float4*)s;
  float4 v1 = *(const float4*)(s + 4);
  uint4 o = make_uint4(pk2(v0.x, v0.y), pk2(v0.z, v0.w),
                       pk2(v1.x, v1.y), pk2(v1.z, v1.w));
  *(uint4*)(dst + ((size_t)g << 3)) = o;
}

__global__ __launch_bounds__(256) void k_cvt_c(
    const float* __restrict__ src, unsigned short* __restrict__ dst)
{
  int g = blockIdx.x * 256 + threadIdx.x;      // 12288*64
  int row = g >> 6, c8 = (g & 63) << 3;
  int b = row / 3072, t = row - b * 3072;
  const float* s = src + ((size_t)((b << 12) + t) << 9) + c8;
  float4 v0 = *(const float4*)s;
  float4 v1 = *(const float4*)(s + 4);
  uint4 o = make_uint4(pk2(v0.x, v0.y), pk2(v0.z, v0.w),
                       pk2(v1.x, v1.y), pk2(v1.z, v1.w));
  *(uint4*)(dst + ((size_t)row << 9) + c8) = o;
}

// ---------------------------------------------------------------------------
// bf16 MFMA GEMM: Out[m][n] = sum_k A[m][k]*W[n][k] + bias[n], K=N=512
// ---------------------------------------------------------------------------
__global__ __launch_bounds__(256) void k_gemm_bf16(
    const unsigned short* __restrict__ A, const unsigned short* __restrict__ W,
    const float* __restrict__ bias, float* __restrict__ Out)
{
  __shared__ unsigned short As[128 * 40];
  __shared__ unsigned short Bs[128 * 40];
  const int tid = threadIdx.x;
  const int row = tid >> 1, half = tid & 1;
  const int bm0 = blockIdx.x << 7, bn0 = blockIdx.y << 7;
  const int wv = tid >> 6, l = tid & 63;
  const int wm0 = (wv & 1) << 6, wn0 = (wv >> 1) << 6;
  const int fr = l & 15, fq = l >> 4;

  const unsigned short* Ap = A + (size_t)(bm0 + row) * CKD + half * 16;
  const unsigned short* Wp = W + (size_t)(bn0 + row) * CKD + half * 16;

  f32x4 acc[4][4];
#pragma unroll
  for (int mt = 0; mt < 4; ++mt)
#pragma unroll
    for (int nt = 0; nt < 4; ++nt) {
      acc[mt][nt][0] = 0.f; acc[mt][nt][1] = 0.f;
      acc[mt][nt][2] = 0.f; acc[mt][nt][3] = 0.f;
    }

  for (int k0 = 0; k0 < CKD; k0 += 32) {
    uint4 av0 = *(const uint4*)(Ap + k0);
    uint4 av1 = *(const uint4*)(Ap + k0 + 8);
    uint4 bv0 = *(const uint4*)(Wp + k0);
    uint4 bv1 = *(const uint4*)(Wp + k0 + 8);
    __syncthreads();
    *(uint4*)&As[row * 40 + half * 16]     = av0;
    *(uint4*)&As[row * 40 + half * 16 + 8] = av1;
    *(uint4*)&Bs[row * 40 + half * 16]     = bv0;
    *(uint4*)&Bs[row * 40 + half * 16 + 8] = bv1;
    __syncthreads();
    bf16x8 af[4], bfr[4];
#pragma unroll
    for (int mt = 0; mt < 4; ++mt)
      af[mt] = *(const bf16x8*)&As[(wm0 + mt * 16 + fr) * 40 + fq * 8];
#pragma unroll
    for (int nt = 0; nt < 4; ++nt)
      bfr[nt] = *(const bf16x8*)&Bs[(wn0 + nt * 16 + fr) * 40 + fq * 8];
#pragma unroll
    for (int mt = 0; mt < 4; ++mt)
#pragma unroll
      for (int nt = 0; nt < 4; ++nt)
        acc[mt][nt] = __builtin_amdgcn_mfma_f32_16x16x32_bf16(
            af[mt], bfr[nt], acc[mt][nt], 0, 0, 0);
  }

#pragma unroll
  for (int nt = 0; nt < 4; ++nt) {
    int col = bn0 + wn0 + nt * 16 + fr;
    float bv = bias[col];
#pragma unroll
    for (int mt = 0; mt < 4; ++mt) {
      int r0 = bm0 + wm0 + mt * 16 + fq * 4;
#pragma unroll
      for (int rg = 0; rg < 4; ++rg)
        Out[(size_t)(r0 + rg) * CKD + col] = acc[mt][nt][rg] + bv;
    }
  }
}

// ---------------------------------------------------------------------------
// Fused decomposition tree: one block stages 16 input rows in LDS and emits
// NL levels (8,4,2,1 output rows) of d/v to the global arenas.
// grid = (pin/16, 4 batches). j0 = first level, pin = rows/batch of Vin.
// ---------------------------------------------------------------------------
__global__ __launch_bounds__(256) void k_decomp_tree(
    const float* __restrict__ Vin, const float* __restrict__ ec_s,
    const float* __restrict__ ec_d, float* __restrict__ DD,
    float* __restrict__ VD, int j0, int NL, int pin)
{
  __shared__ float Es[128], Ed[128];
  __shared__ float bufA[16 * 512];
  __shared__ float bufB[8 * 512];
  const int tid = threadIdx.x;
  if (tid < 128) Es[tid] = ec_s[tid];
  else Ed[tid - 128] = ec_d[tid - 128];
  const int b = blockIdx.y;
  const int t0 = blockIdx.x << 4;

  const float* src = Vin + ((size_t)b * pin + t0) * CKD;
  for (int q = tid; q < 16 * 128; q += 256) {
    int rr = q >> 7, c4 = (q & 127) << 2;
    *(float4*)&bufA[rr * 512 + c4] = *(const float4*)(src + (size_t)rr * CKD + c4);
  }
  __syncthreads();

  float* rd = bufA;
  float* wr = bufB;
  for (int lv = 0; lv < NL; ++lv) {
    const int j = j0 + lv;
    const int Lout = 4096 >> j;
    const int rows = 8 >> lv;
    const int sb = t0 >> (lv + 1);
    const size_t base = 4ull * (4096 - (4096 >> (j - 1))) * CKD;
    float* Dp = DD + base;
    float* Vp = VD + base;
    for (int task = tid; task < rows * 64; task += 256) {
      int s = task >> 6, c = task & 63;
      const float* r0p = rd + (2 * s) * 512 + (c << 3);
      float a[16];
      float4 v0 = *(const float4*)r0p;
      float4 v1 = *(const float4*)(r0p + 4);
      float4 v2 = *(const float4*)(r0p + 512);
      float4 v3 = *(const float4*)(r0p + 516);
      a[0]=v0.x; a[1]=v0.y; a[2]=v0.z; a[3]=v0.w; a[4]=v1.x; a[5]=v1.y; a[6]=v1.z; a[7]=v1.w;
      a[8]=v2.x; a[9]=v2.y; a[10]=v2.z; a[11]=v2.w; a[12]=v3.x; a[13]=v3.y; a[14]=v3.z; a[15]=v3.w;
      float dv[8] = {}, vv[8] = {};
#pragma unroll
      for (int m = 0; m < 16; ++m)
#pragma unroll
        for (int k = 0; k < 8; ++k) {
          dv[k] += a[m] * Ed[m * 8 + k];
          vv[k] += a[m] * Es[m * 8 + k];
        }
      size_t orow = ((size_t)b * Lout + sb + s) * CKD + (c << 3);
      *(float4*)(Dp + orow)     = make_float4(dv[0], dv[1], dv[2], dv[3]);
      *(float4*)(Dp + orow + 4) = make_float4(dv[4], dv[5], dv[6], dv[7]);
      *(float4*)(Vp + orow)     = make_float4(vv[0], vv[1], vv[2], vv[3]);
      *(float4*)(Vp + orow + 4) = make_float4(vv[4], vv[5], vv[6], vv[7]);
      if (lv + 1 < NL) {
        float* wp = wr + s * 512 + (c << 3);
        *(float4*)wp       = make_float4(vv[0], vv[1], vv[2], vv[3]);
        *(float4*)(wp + 4) = make_float4(vv[4], vv[5], vv[6], vv[7]);
      }
    }
    __syncthreads();
    float* t = rd; rd = wr; wr = t;
  }
}

// ---------------------------------------------------------------------------
// T0
// ---------------------------------------------------------------------------
__global__ __launch_bounds__(256) void k_t0(
    const float* __restrict__ Vin, const float* __restrict__ T0w,
    const float* __restrict__ T0b, float* __restrict__ Out)
{
  int g = blockIdx.x * 256 + threadIdx.x;
  if (g >= 4 * 2 * 64) return;
  int c = g & 63;
  int t = (g >> 6) & 1;
  int b = g >> 7;
  const float* src = Vin + ((size_t)(b * 2 + t)) * CKD + (c << 3);
  float a[8];
  float4 v0 = *(const float4*)src;
  float4 v1 = *(const float4*)(src + 4);
  a[0]=v0.x; a[1]=v0.y; a[2]=v0.z; a[3]=v0.w; a[4]=v1.x; a[5]=v1.y; a[6]=v1.z; a[7]=v1.w;
  float o[8];
#pragma unroll
  for (int ko = 0; ko < 8; ++ko) {
    float sum = T0b[ko];
#pragma unroll
    for (int k = 0; k < 8; ++k) sum += a[k] * T0w[ko * 8 + k];
    o[ko] = sum;
  }
  float* dst = Out + ((size_t)(b * 2 + t)) * CKD + (c << 3);
  *(float4*)dst       = make_float4(o[0], o[1], o[2], o[3]);
  *(float4*)(dst + 4) = make_float4(o[4], o[5], o[6], o[7]);
}

// ---------------------------------------------------------------------------
// Forward truncated DFT, t-chunk = 64, 4-deep software pipeline.
// Multi-chunk levels (L>64) write per-chunk partials to Scr (deterministic,
// reduced by k_fdft_red); single-chunk levels store directly.
// NO atomics -> bit-identical on every launch.
// ---------------------------------------------------------------------------
__global__ __launch_bounds__(256) void k_fdft(
    const float* __restrict__ DD, const float* __restrict__ VD,
    float* __restrict__ Scr,
    float* __restrict__ XDre, float* __restrict__ XDim,
    float* __restrict__ XVre, float* __restrict__ XVim)
{
  __shared__ float2 tw[1024];  // [f][64]
  int bx = blockIdx.x, j = 1;
  for (;;) {
    int c = (4096 >> j) >> 6; if (c < 1) c = 1;
    if (bx < c) break;
    bx -= c; ++j;
  }
  const int L = 4096 >> j;
  const int t0 = bx << 6;
  const int tcnt = imin(64, L - t0);
  const bool multi = (L > 64);
  const int b = blockIdx.y;
  const int z = blockIdx.z;
  const int r = (j - 1) * 4 + b;
  const float* src = (z ? VD : DD) +
      ((size_t)(4 * (4096 - (4096 >> (j - 1))) + b * L)) * CKD;
  float* dre = z ? XVre : XDre;
  float* dim_ = z ? XVim : XDim;

  for (int idx = threadIdx.x; idx < 1024; idx += 256) {
    int ff = idx >> 6, tl = idx & 63;
    int t = t0 + tl;
    int m = (2 * ff * t) & (2 * L - 1);
    float xang = (float)m / (float)L;
    tw[idx] = make_float2(cospif(xang), sinpif(xang));
  }
  __syncthreads();

  float ar[16][2] = {};
  float ai[16][2] = {};
  const float* sp = src + (size_t)t0 * CKD + (threadIdx.x << 1);

  if (tcnt >= 4) {
    // tcnt is one of {4,8,16,32,64} here -> always a multiple of 4
    float2 q0 = *(const float2*)(sp + 0 * (size_t)CKD);
    float2 q1 = *(const float2*)(sp + 1 * (size_t)CKD);
    float2 q2 = *(const float2*)(sp + 2 * (size_t)CKD);
    float2 q3 = *(const float2*)(sp + 3 * (size_t)CKD);
    int tl = 0;
    for (;;) {
      float2 x0 = q0, x1 = q1, x2 = q2, x3 = q3;
      const int nx = tl + 4;
      if (nx < tcnt) {
        q0 = *(const float2*)(sp + (size_t)(nx + 0) * CKD);
        q1 = *(const float2*)(sp + (size_t)(nx + 1) * CKD);
        q2 = *(const float2*)(sp + (size_t)(nx + 2) * CKD);
        q3 = *(const float2*)(sp + (size_t)(nx + 3) * CKD);
      }
#pragma unroll
      for (int ff = 0; ff < 16; ++ff) {
        float2 c0 = tw[(ff << 6) + tl + 0];
        float2 c1 = tw[(ff << 6) + tl + 1];
        float2 c2 = tw[(ff << 6) + tl + 2];
        float2 c3 = tw[(ff << 6) + tl + 3];
        ar[ff][0] += x0.x * c0.x; ar[ff][1] += x0.y * c0.x;
        ai[ff][0] -= x0.x * c0.y; ai[ff][1] -= x0.y * c0.y;
        ar[ff][0] += x1.x * c1.x; ar[ff][1] += x1.y * c1.x;
        ai[ff][0] -= x1.x * c1.y; ai[ff][1] -= x1.y * c1.y;
        ar[ff][0] += x2.x * c2.x; ar[ff][1] += x2.y * c2.x;
        ai[ff][0] -= x2.x * c2.y; ai[ff][1] -= x2.y * c2.y;
        ar[ff][0] += x3.x * c3.x; ar[ff][1] += x3.y * c3.x;
        ai[ff][0] -= x3.x * c3.y; ai[ff][1] -= x3.y * c3.y;
      }
      tl = nx;
      if (tl >= tcnt) break;
    }
  } else {
    // deepest level: tcnt == 2
    for (int tl = 0; tl < tcnt; ++tl) {
      float2 xv = *(const float2*)(sp + (size_t)tl * CKD);
#pragma unroll
      for (int ff = 0; ff < 16; ++ff) {
        float2 cs = tw[(ff << 6) + tl];
        ar[ff][0] += xv.x * cs.x; ar[ff][1] += xv.y * cs.x;
        ai[ff][0] -= xv.x * cs.y; ai[ff][1] -= xv.y * cs.y;
      }
    }
  }

  const int i0 = threadIdx.x << 1;
  if (multi) {
    // partial slot: (chunk, b, z); chunk = chunks-before-level-j + bx
    const int chunk = 64 - (64 >> (j - 1)) + bx;
    float* S = Scr + ((size_t)((((chunk << 2) + b) << 1) + z)) * 16384;
#pragma unroll
    for (int ff = 0; ff < 16; ++ff) {
      *(float2*)(S + (ff << 10) + i0)       = make_float2(ar[ff][0], ar[ff][1]);
      *(float2*)(S + (ff << 10) + 512 + i0) = make_float2(ai[ff][0], ai[ff][1]);
    }
  } else {
#pragma unroll
    for (int ff = 0; ff < 16; ++ff) {
      size_t bidx = ((size_t)ff * NROWS + r) * CKD + i0;
      *(float2*)(dre + bidx)  = make_float2(ar[ff][0], ar[ff][1]);
      *(float2*)(dim_ + bidx) = make_float2(ai[ff][0], ai[ff][1]);
    }
  }
}

// ---------------------------------------------------------------------------
// Deterministic reduction of per-chunk DFT partials -> XD*/XV* rows 0..19.
// One thread per (r<20, z, ff, part, i); sums chunks in fixed order.
// ---------------------------------------------------------------------------
__global__ __launch_bounds__(256) void k_fdft_red(
    const float* __restrict__ Scr,
    float* __restrict__ XDre, float* __restrict__ XDim,
    float* __restrict__ XVre, float* __restrict__ XVim)
{
  int g = blockIdx.x * 256 + threadIdx.x;   // 20*2*16*2*512 = 655360
  int i = g & 511;
  int part = (g >> 9) & 1;
  int ff = (g >> 10) & 15;
  int z = (g >> 14) & 1;
  int r = g >> 15;            // 0..19
  int jidx = r >> 2;          // level-1: 0..4
  int b = r & 3;
  int c = 32 >> jidx;         // chunks in this level: 32,16,8,4,2
  int cbase = 64 - (64 >> jidx);
  const float* base = Scr
      + ((size_t)((((cbase << 2) + b) << 1) + z)) * 16384
      + (ff << 10) + (part << 9) + i;
  const size_t STR = 8ull * 16384;  // slot stride between consecutive chunks
  float s0 = 0.f, s1 = 0.f, s2 = 0.f, s3 = 0.f;
  int k = 0;
  for (; k + 4 <= c; k += 4) {
    s0 += base[(size_t)(k + 0) * STR];
    s1 += base[(size_t)(k + 1) * STR];
    s2 += base[(size_t)(k + 2) * STR];
    s3 += base[(size_t)(k + 3) * STR];
  }
  for (; k < c; ++k) s0 += base[(size_t)k * STR];
  float s = (s0 + s1) + (s2 + s3);
  float* dst = part ? (z ? XVim : XDim) : (z ? XVre : XDre);
  dst[((size_t)ff * NROWS + r) * CKD + i] = s;
}

// ---------------------------------------------------------------------------
// Weight repack to packed bf16, planar outputs W4lo/W4hi/W2b ([f][g] u32).
// No LDS, no barriers: thread g reads its own 64B line from re and im
// (the "transpose" is free -- one output g consumes one full input line).
// Rounds 5-9 lesson: every LDS-transpose variant capped at 2.2 TB/s because
// barrier drains chop the memory pipeline; the barrier-free per-thread-
// contiguous pattern hit 3.2 TB/s back in round 4.
// grid = (1024, 3): blockIdx.y picks the (re,im,dst) phase.
// ---------------------------------------------------------------------------
__global__ __launch_bounds__(256) void k_transw6b(
    const float* __restrict__ sAr, const float* __restrict__ sAi,
    const float* __restrict__ sBr, const float* __restrict__ sBi,
    const float* __restrict__ sCr, const float* __restrict__ sCi,
    uint32* __restrict__ W4lo, uint32* __restrict__ W4hi,
    uint32* __restrict__ W2b)
{
  const int tid = threadIdx.x;
  const int g = (blockIdx.x << 8) + tid;
  const int p = blockIdx.y;
  const float* re = (p == 0) ? sAr : (p == 1) ? sBr : sCr;
  const float* im = (p == 0) ? sAi : (p == 1) ? sBi : sCi;
  uint32* dst = (p == 0) ? W4lo : (p == 1) ? W4hi : W2b;

  const size_t sb = (size_t)g * 16;
  float4 r0 = *(const float4*)(re + sb);
  float4 r1 = *(const float4*)(re + sb + 4);
  float4 r2 = *(const float4*)(re + sb + 8);
  float4 r3 = *(const float4*)(re + sb + 12);
  float4 i0 = *(const float4*)(im + sb);
  float4 i1 = *(const float4*)(im + sb + 4);
  float4 i2 = *(const float4*)(im + sb + 8);
  float4 i3 = *(const float4*)(im + sb + 12);

  dst[(0ull  << 18) + g] = pk2(r0.x, i0.x);
  dst[(1ull  << 18) + g] = pk2(r0.y, i0.y);
  dst[(2ull  << 18) + g] = pk2(r0.z, i0.z);
  dst[(3ull  << 18) + g] = pk2(r0.w, i0.w);
  dst[(4ull  << 18) + g] = pk2(r1.x, i1.x);
  dst[(5ull  << 18) + g] = pk2(r1.y, i1.y);
  dst[(6ull  << 18) + g] = pk2(r1.z, i1.z);
  dst[(7ull  << 18) + g] = pk2(r1.w, i1.w);
  dst[(8ull  << 18) + g] = pk2(r2.x, i2.x);
  dst[(9ull  << 18) + g] = pk2(r2.y, i2.y);
  dst[(10ull << 18) + g] = pk2(r2.z, i2.z);
  dst[(11ull << 18) + g] = pk2(r2.w, i2.w);
  dst[(12ull << 18) + g] = pk2(r3.x, i3.x);
  dst[(13ull << 18) + g] = pk2(r3.y, i3.y);
  dst[(14ull << 18) + g] = pk2(r3.z, i3.z);
  dst[(15ull << 18) + g] = pk2(r3.w, i3.w);
}

// ---------------------------------------------------------------------------
// Pack spectral X -> bf16 MFMA A-matrices
// ---------------------------------------------------------------------------
__global__ __launch_bounds__(256) void k_packA(
    const float* __restrict__ XDre, const float* __restrict__ XDim,
    const float* __restrict__ XVre, const float* __restrict__ XVim,
    unsigned short* __restrict__ Aud, unsigned short* __restrict__ Aus)
{
  int g = blockIdx.x * 256 + threadIdx.x;   // 16 * 48 * 128
  int f = g / 6144;
  int rem = g - f * 6144;
  int r = rem >> 7, iq = rem & 127;
  uint4 w0 = make_uint4(0,0,0,0), w1 = w0, wu = w0;
  if (r < NROWS) {
    size_t base = ((size_t)f * NROWS + r) * CKD + (iq << 2);
    float4 dre = *(const float4*)(XDre + base);
    float4 dim_ = *(const float4*)(XDim + base);
    float4 vre = *(const float4*)(XVre + base);
    float4 vim = *(const float4*)(XVim + base);
    w0 = make_uint4(pk2(dre.x, dim_.x), pk2(vre.x, vim.x),
                    pk2(dre.y, dim_.y), pk2(vre.y, vim.y));
    w1 = make_uint4(pk2(dre.z, dim_.z), pk2(vre.z, vim.z),
                    pk2(dre.w, dim_.w), pk2(vre.w, vim.w));
    wu = make_uint4(pk2(dre.x, dim_.x), pk2(dre.y, dim_.y),
                    pk2(dre.z, dim_.z), pk2(dre.w, dim_.w));
  }
  size_t du = ((size_t)f * 48 + r) * 2048 + (iq << 4);
  *(uint4*)(Aud + du)     = w0;
  *(uint4*)(Aud + du + 8) = w1;
  *(uint4*)(Aus + ((size_t)f * 48 + r) * 1024 + (iq << 3)) = wu;
}

// ---------------------------------------------------------------------------
// MFMA channel mix; partials -> Part[is][plane][f*44+r][o]
// W4 planar (W4lo/W4hi): stage two 8B loads, reassemble into sBud.
// ---------------------------------------------------------------------------
__global__ __launch_bounds__(256) void k_mixmm(
    const uint32* __restrict__ W4lo, const uint32* __restrict__ W4hi,
    const uint32* __restrict__ W2b,
    const unsigned short* __restrict__ Aud, const unsigned short* __restrict__ Aus,
    float* __restrict__ Part)
{
  __shared__ __attribute__((aligned(16))) uint2 sBud[16 * 130];
  __shared__ __attribute__((aligned(16))) uint32 sBus[16 * 132];
  __shared__ __attribute__((aligned(16))) unsigned short sAud[48 * 72];
  __shared__ __attribute__((aligned(16))) unsigned short sAus[48 * 40];

  const int f = blockIdx.x;
  const int o0 = blockIdx.y << 7;
  const int is = blockIdx.z;
  const int i0 = is << 7;
  const int tid = threadIdx.x;
  const int w = tid >> 6, l = tid & 63;
  const int fr = l & 15, fq = l >> 4;
  const int ow0 = w << 5;

  const uint32* gWlo = W4lo + ((size_t)f << 18);
  const uint32* gWhi = W4hi + ((size_t)f << 18);
  const uint32* gW2 = W2b + ((size_t)f << 18);
  const unsigned short* gAud = Aud + (size_t)f * 48 * 2048;
  const unsigned short* gAus = Aus + (size_t)f * 48 * 1024;

  f32x4 aUd[3][2][2], aUs[3][2][2];
#pragma unroll
  for (int m = 0; m < 3; ++m)
#pragma unroll
    for (int ot = 0; ot < 2; ++ot)
#pragma unroll
      for (int cp = 0; cp < 2; ++cp) {
        aUd[m][ot][cp][0]=0.f; aUd[m][ot][cp][1]=0.f; aUd[m][ot][cp][2]=0.f; aUd[m][ot][cp][3]=0.f;
        aUs[m][ot][cp][0]=0.f; aUs[m][ot][cp][1]=0.f; aUs[m][ot][cp][2]=0.f; aUs[m][ot][cp][3]=0.f;
      }

  for (int ic = 0; ic < 8; ++ic) {
    const int ig = i0 + (ic << 4);
    __syncthreads();
#pragma unroll
    for (int n = 0; n < 4; ++n) {
      int q = tid + (n << 8);
      int il = q >> 6, op = (q & 63) << 1;
      size_t gi = (size_t)(ig + il) * 512 + o0 + op;
      uint2 lo2 = *(const uint2*)(gWlo + gi);
      uint2 hi2 = *(const uint2*)(gWhi + gi);
      *(uint4*)&sBud[il * 130 + op] = make_uint4(lo2.x, hi2.x, lo2.y, hi2.y);
    }
#pragma unroll
    for (int n = 0; n < 2; ++n) {
      int q = tid + (n << 8);
      int il = q >> 5, oq = (q & 31) << 2;
      uint4 v = *(const uint4*)(gW2 + (size_t)(ig + il) * 512 + o0 + oq);
      *(uint4*)&sBus[il * 132 + oq] = v;
    }
    {
      int q = tid;
      int m = q >> 3, k8 = (q & 7) << 3;
      uint4 v = *(const uint4*)(gAud + (size_t)m * 2048 + (is << 9) + (ic << 6) + k8);
      *(uint4*)&sAud[m * 72 + k8] = v;
      q = tid + 256;
      if (q < 384) {
        m = q >> 3; k8 = (q & 7) << 3;
        uint4 v2 = *(const uint4*)(gAud + (size_t)m * 2048 + (is << 9) + (ic << 6) + k8);
        *(uint4*)&sAud[m * 72 + k8] = v2;
      }
    }
    if (tid < 192) {
      int m = tid >> 2, k8 = (tid & 3) << 3;
      uint4 v = *(const uint4*)(gAus + (size_t)m * 1024 + (is << 8) + (ic << 5) + k8);
      *(uint4*)&sAus[m * 40 + k8] = v;
    }
    __syncthreads();

#pragma unroll
    for (int ks = 0; ks < 2; ++ks) {
      bf16x8 af[3];
#pragma unroll
      for (int m = 0; m < 3; ++m)
        af[m] = *(const bf16x8*)&sAud[(m * 16 + fr) * 72 + (ks << 5) + (fq << 3)];
#pragma unroll
      for (int ot = 0; ot < 2; ++ot) {
        int ol = ow0 + (ot << 4) + fr;
        int il = (ks << 3) + (fq << 1);
        uint2 qa = sBud[il * 130 + ol];
        uint2 qb = sBud[(il + 1) * 130 + ol];
        bf16x8 b0 = mk_neghi(qa.x, qa.y, qb.x, qb.y);
        bf16x8 b1 = mk_swap(qa.x, qa.y, qb.x, qb.y);
#pragma unroll
        for (int m = 0; m < 3; ++m) {
          aUd[m][ot][0] = __builtin_amdgcn_mfma_f32_16x16x32_bf16(af[m], b0, aUd[m][ot][0], 0, 0, 0);
          aUd[m][ot][1] = __builtin_amdgcn_mfma_f32_16x16x32_bf16(af[m], b1, aUd[m][ot][1], 0, 0, 0);
        }
      }
    }
    {
      bf16x8 af[3];
#pragma unroll
      for (int m = 0; m < 3; ++m)
        af[m] = *(const bf16x8*)&sAus[(m * 16 + fr) * 40 + (fq << 3)];
#pragma unroll
      for (int ot = 0; ot < 2; ++ot) {
        int ol = ow0 + (ot << 4) + fr;
        int il = fq << 2;
        uint32 q0 = sBus[(il + 0) * 132 + ol];
        uint32 q1 = sBus[(il + 1) * 132 + ol];
        uint32 q2 = sBus[(il + 2) * 132 + ol];
        uint32 q3 = sBus[(il + 3) * 132 + ol];
        bf16x8 b0 = mk_neghi(q0, q1, q2, q3);
        bf16x8 b1 = mk_swap(q0, q1, q2, q3);
#pragma unroll
        for (int m = 0; m < 3; ++m) {
          aUs[m][ot][0] = __builtin_amdgcn_mfma_f32_16x16x32_bf16(af[m], b0, aUs[m][ot][0], 0, 0, 0);
          aUs[m][ot][1] = __builtin_amdgcn_mfma_f32_16x16x32_bf16(af[m], b1, aUs[m][ot][1], 0, 0, 0);
        }
      }
    }
  }

  float* P = Part + (size_t)is * 4 * XPLANE;
#pragma unroll
  for (int m = 0; m < 3; ++m) {
#pragma unroll
    for (int reg = 0; reg < 4; ++reg) {
      int r = m * 16 + (fq << 2) + reg;
      if (r < NROWS) {
        size_t rb = ((size_t)f * NROWS + r) * CKD;
#pragma unroll
        for (int ot = 0; ot < 2; ++ot) {
          int col = o0 + ow0 + (ot << 4) + fr;
          P[0 * XPLANE + rb + col] = aUd[m][ot][0][reg];
          P[1 * XPLANE + rb + col] = aUd[m][ot][1][reg];
          P[2 * XPLANE + rb + col] = aUs[m][ot][0][reg];
          P[3 * XPLANE + rb + col] = aUs[m][ot][1][reg];
        }
      }
    }
  }
}

// ---------------------------------------------------------------------------
// Reduce 4 i-split partials -> interleaved complex spectral arrays:
// UdFc/UsFc layout [row][i][re|im], row = f*NROWS + r (1024 floats per row).
// ---------------------------------------------------------------------------
__global__ __launch_bounds__(256) void k_reduce4(
    const float* __restrict__ Part,
    float* __restrict__ UdFc, float* __restrict__ UsFc)
{
  int idx = blockIdx.x * 256 + threadIdx.x;
  if (idx >= XPLANE) return;
  float s0 = 0.f, s1 = 0.f, s2 = 0.f, s3 = 0.f;
#pragma unroll
  for (int is = 0; is < 4; ++is) {
    const float* p = Part + (size_t)is * 4 * XPLANE;
    s0 += p[0 * XPLANE + idx];
    s1 += p[1 * XPLANE + idx];
    s2 += p[2 * XPLANE + idx];
    s3 += p[3 * XPLANE + idx];
  }
  int row = idx >> 9, i = idx & 511;
  size_t base = ((size_t)row << 10) + (i << 1);
  *(float2*)(UdFc + base) = make_float2(s0, s1);
  *(float2*)(UsFc + base) = make_float2(s2, s3);
}

// ---------------------------------------------------------------------------
// Fallback scalar mix (workspace too small for repack arenas); writes the
// same interleaved UdFc/UsFc layout.
// ---------------------------------------------------------------------------
__global__ __launch_bounds__(512) void k_mix_fb(
    const float* __restrict__ XDre, const float* __restrict__ XDim,
    const float* __restrict__ XVre, const float* __restrict__ XVim,
    const float* __restrict__ war, const float* __restrict__ wai,
    const float* __restrict__ wbr, const float* __restrict__ wbi,
    const float* __restrict__ wcr, const float* __restrict__ wci,
    float* __restrict__ UdFc, float* __restrict__ UsFc)
{
  const int f = blockIdx.x;
  const int ot = blockIdx.y;
  const int lane = threadIdx.x & 63;
  const int rg = threadIdx.x >> 6;
  const int rbase = (rg < 4) ? rg * 6 : 24 + (rg - 4) * 5;
  const int rcnt = (rg < 4) ? 6 : 5;
  const int o0 = (ot << 7) + lane;
  __shared__ float4 sx[NROWS * 64];
  float udr[6][2] = {}, udi[6][2] = {}, usr[6][2] = {}, usi[6][2] = {};
  for (int i0 = 0; i0 < 512; i0 += 64) {
    __syncthreads();
    for (int idx = threadIdx.x; idx < NROWS * 64; idx += 512) {
      int r = idx >> 6, il = idx & 63;
      size_t xb = ((size_t)f * NROWS + r) * CKD + i0 + il;
      sx[idx] = make_float4(XDre[xb], XDim[xb], XVre[xb], XVim[xb]);
    }
    __syncthreads();
    for (int ii = 0; ii < 64; ++ii) {
      int i = i0 + ii;
      size_t wo = ((((size_t)i << 9) + o0) << 4) + f;
      float4 wa0 = make_float4(war[wo], wai[wo], wbr[wo], wbi[wo]);
      float2 wc0 = make_float2(wcr[wo], wci[wo]);
      size_t w1 = wo + (64u << 4);
      float4 wa1 = make_float4(war[w1], wai[w1], wbr[w1], wbi[w1]);
      float2 wc1 = make_float2(wcr[w1], wci[w1]);
#pragma unroll
      for (int rr = 0; rr < 6; ++rr) {
        if (rr < rcnt) {
          float4 xv = sx[((rbase + rr) << 6) + ii];
          udr[rr][0] += xv.x * wa0.x - xv.y * wa0.y + xv.z * wa0.z - xv.w * wa0.w;
          udi[rr][0] += xv.x * wa0.y + xv.y * wa0.x + xv.z * wa0.w + xv.w * wa0.z;
          usr[rr][0] += xv.x * wc0.x - xv.y * wc0.y;
          usi[rr][0] += xv.x * wc0.y + xv.y * wc0.x;
          udr[rr][1] += xv.x * wa1.x - xv.y * wa1.y + xv.z * wa1.z - xv.w * wa1.w;
          udi[rr][1] += xv.x * wa1.y + xv.y * wa1.x + xv.z * wa1.w + xv.w * wa1.z;
          usr[rr][1] += xv.x * wc1.x - xv.y * wc1.y;
          usi[rr][1] += xv.x * wc1.y + xv.y * wc1.x;
        }
      }
    }
  }
#pragma unroll
  for (int rr = 0; rr < 6; ++rr) {
    if (rr < rcnt) {
      size_t base = ((size_t)(f * NROWS + rbase + rr)) << 10;
      *(float2*)(UdFc + base + (o0 << 1))        = make_float2(udr[rr][0], udi[rr][0]);
      *(float2*)(UdFc + base + ((o0 + 64) << 1)) = make_float2(udr[rr][1], udi[rr][1]);
      *(float2*)(UsFc + base + (o0 << 1))        = make_float2(usr[rr][0], usi[rr][0]);
      *(float2*)(UsFc + base + ((o0 + 64) << 1)) = make_float2(usr[rr][1], usi[rr][1]);
    }
  }
}

// ---------------------------------------------------------------------------
// Inverse truncated DFT. Interleaved UdFc/UsFc ([row][i][re|im]) float4
// loads. All accumulator indices compile-time constant (SROA -> VGPRs).
// ---------------------------------------------------------------------------
__global__ __launch_bounds__(256) void k_idft(
    const float* __restrict__ UdFc, const float* __restrict__ UsFc,
    float* __restrict__ UdT, float* __restrict__ UsT)
{
  __shared__ float2 tw[128];  // [f][8]
  int bx = blockIdx.x, j = 1;
  for (;;) {
    int c = (4096 >> j) >> 3; if (c < 1) c = 1;
    if (bx < c) break;
    bx -= c; ++j;
  }
  const int L = 4096 >> j;
  const int l = imin(16, (L >> 1) + 1);
  const int t0 = bx << 3;
  const int b = blockIdx.y;
  const int r = (j - 1) * 4 + b;
  if (threadIdx.x < 128) {
    int ff = threadIdx.x >> 3, tl = threadIdx.x & 7;
    int t = t0 + tl;
    int m = (2 * ff * t) & (2 * L - 1);
    float xang = (float)m / (float)L;
    float wgt = (ff == 0 || 2 * ff == L) ? 1.0f : 2.0f;
    float sc = wgt / (float)L;
    tw[threadIdx.x] = make_float2(cospif(xang) * sc, sinpif(xang) * sc);
  }
  __syncthreads();
  const size_t FS = (size_t)NROWS * 1024;  // stride between ff planes
  const float* pU = UdFc + ((size_t)r << 10) + (threadIdx.x << 2);
  const float* pS = UsFc + ((size_t)r << 10) + (threadIdx.x << 2);

  float2 ud[8], us[8];
#pragma unroll
  for (int tl = 0; tl < 8; ++tl) { ud[tl] = make_float2(0.f, 0.f); us[tl] = make_float2(0.f, 0.f); }

  for (int ff = 0; ff < l; ++ff) {
    float4 uv = *(const float4*)(pU + (size_t)ff * FS);
    float4 sv = *(const float4*)(pS + (size_t)ff * FS);
#pragma unroll
    for (int tl = 0; tl < 8; ++tl) {
      float2 cs = tw[(ff << 3) + tl];
      ud[tl].x += uv.x * cs.x - uv.y * cs.y;
      ud[tl].y += uv.z * cs.x - uv.w * cs.y;
      us[tl].x += sv.x * cs.x - sv.y * cs.y;
      us[tl].y += sv.z * cs.x - sv.w * cs.y;
    }
  }

  const int tmax = imin(8, L - t0);   // <8 only for the 2 deepest levels
  const int o = threadIdx.x << 1;
  size_t obase = ((size_t)(4 * (4096 - (4096 >> (j - 1))) + b * L + t0)) * CKD + o;
#pragma unroll
  for (int tl = 0; tl < 8; ++tl) {    // constant tl -> SROA keeps ud/us in VGPRs
    if (tl < tmax) {
      *(float2*)(UdT + obase + (size_t)tl * CKD) = ud[tl];
      *(float2*)(UsT + obase + (size_t)tl * CKD) = us[tl];
    }
  }
}

// ---------------------------------------------------------------------------
// Fused reconstruction tree: block loads ir input rows, expands NL levels in
// LDS (intermediate v never hits global), writes ir<<NL rows to Vout.
// grid = (LcIn/ir, 4). Levels processed: j0, j0-1, ..., j0-NL+1.
// ---------------------------------------------------------------------------
__global__ __launch_bounds__(256) void k_recon_tree(
    const float* __restrict__ Vin, const float* __restrict__ UdT,
    const float* __restrict__ UsT, const float* __restrict__ rc_e,
    const float* __restrict__ rc_o, float* __restrict__ Vout,
    int j0, int NL, int ir, int pin, int pout)
{
  __shared__ float Re[128], Ro[128];
  __shared__ float bufA[16 * 512];
  __shared__ float bufB[16 * 512];
  const int tid = threadIdx.x;
  if (tid < 128) Re[tid] = rc_e[tid];
  else Ro[tid - 128] = rc_o[tid - 128];
  const int b = blockIdx.y;
  const int r0 = blockIdx.x * ir;

  for (int q = tid; q < ir * 128; q += 256) {
    int rr = q >> 7, c4 = (q & 127) << 2;
    *(float4*)&bufA[rr * 512 + c4] =
        *(const float4*)(Vin + ((size_t)b * pin + r0 + rr) * CKD + c4);
  }
  __syncthreads();

  float* rd = bufA;
  float* wr = bufB;
  int rows = ir;
  for (int m = 0; m < NL; ++m) {
    const int j = j0 - m;
    const int Lc = 4096 >> j;
    const size_t ab = 4ull * (4096 - (4096 >> (j - 1))) * CKD;
    const int g0 = r0 << m;
    for (int task = tid; task < rows * 64; task += 256) {
      int s = task >> 6, c = task & 63;
      size_t arow = ab + ((size_t)b * Lc + g0 + s) * CKD + (c << 3);
      const float* vp = rd + s * 512 + (c << 3);
      float a[16];
      {
        float4 t0_ = *(const float4*)vp;
        float4 t1_ = *(const float4*)(vp + 4);
        float4 u0 = *(const float4*)(UsT + arow);
        float4 u1 = *(const float4*)(UsT + arow + 4);
        a[0]=t0_.x+u0.x; a[1]=t0_.y+u0.y; a[2]=t0_.z+u0.z; a[3]=t0_.w+u0.w;
        a[4]=t1_.x+u1.x; a[5]=t1_.y+u1.y; a[6]=t1_.z+u1.z; a[7]=t1_.w+u1.w;
        float4 d0 = *(const float4*)(UdT + arow);
        float4 d1 = *(const float4*)(UdT + arow + 4);
        a[8]=d0.x; a[9]=d0.y; a[10]=d0.z; a[11]=d0.w;
        a[12]=d1.x; a[13]=d1.y; a[14]=d1.z; a[15]=d1.w;
      }
      float xe[8] = {}, xo[8] = {};
#pragma unroll
      for (int mm = 0; mm < 16; ++mm)
#pragma unroll
        for (int k = 0; k < 8; ++k) {
          xe[k] += a[mm] * Re[mm * 8 + k];
          xo[k] += a[mm] * Ro[mm * 8 + k];
        }
      float* we = wr + (2 * s) * 512 + (c << 3);
      *(float4*)we         = make_float4(xe[0], xe[1], xe[2], xe[3]);
      *(float4*)(we + 4)   = make_float4(xe[4], xe[5], xe[6], xe[7]);
      *(float4*)(we + 512) = make_float4(xo[0], xo[1], xo[2], xo[3]);
      *(float4*)(we + 516) = make_float4(xo[4], xo[5], xo[6], xo[7]);
    }
    __syncthreads();
    float* t = rd; rd = wr; wr = t;
    rows <<= 1;
  }

  for (int q = tid; q < rows * 128; q += 256) {
    int rr = q >> 7, c4 = (q & 127) << 2;
    *(float4*)(Vout + ((size_t)b * pout + (r0 << NL) + rr) * CKD + c4) =
        *(const float4*)&rd[rr * 512 + c4];
  }
}

// ---------------------------------------------------------------------------
extern "C" void kernel_launch(void* const* d_in, const int* in_sizes, int n_in,
                              void* d_out, int out_size, void* d_ws, size_t ws_size,
                              hipStream_t stream)
{
  const float* x     = (const float*)d_in[0];
  const float* Lk0_w = (const float*)d_in[1];
  const float* Lk0_b = (const float*)d_in[2];
  const float* Lk1_w = (const float*)d_in[3];
  const float* Lk1_b = (const float*)d_in[4];
  const float* T0_w  = (const float*)d_in[5];
  const float* T0_b  = (const float*)d_in[6];
  const float* Ar = (const float*)d_in[7];
  const float* Ai = (const float*)d_in[8];
  const float* Br = (const float*)d_in[9];
  const float* Bi = (const float*)d_in[10];
  const float* Cr = (const float*)d_in[11];
  const float* Ci = (const float*)d_in[12];
  const float* ec_s = (const float*)d_in[13];
  const float* ec_d = (const float*)d_in[14];
  const float* rc_e = (const float*)d_in[15];
  const float* rc_o = (const float*)d_in[16];
  float* out = (float*)d_out;

  // workspace layout (floats)
  float* w = (float*)d_ws;
  float* V0 = w;   w += (size_t)4 * 4096 * 512;  // RA rows 0..7; SA/SB stages
  float* VD = w;   w += (size_t)4 * 4094 * 512;  // aliased as UsT
  float* DD = w;   w += (size_t)4 * 4094 * 512;  // aliased as UdT; late: Cb
  float* RB = w;   w += (size_t)4 * 4096 * 512;  // early: Xb; mid: fdft-Scr, Part; late: recon out
  float* XDre = w; w += XPLANE;
  float* XDim = w; w += XPLANE;
  float* XVre = w; w += XPLANE;
  float* XVim = w; w += XPLANE;
  float* UdFc = w; w += 2 * XPLANE;  // interleaved [row][i][re|im]; early: Wb0/Wb1 bf16
  float* UsFc = w; w += 2 * XPLANE;
  float* WT = w;
  float* RA = V0;
  float* SA = V0 + 4096;            // 4*16*512 = 32768 floats
  float* SB = V0 + 4096 + 32768;    // 4*256*512 = 524288 floats
  float* UdT = DD;
  float* UsT = VD;
  float* Part = RB;                 // 16*XPLANE = 5.77M <= 8.39M
  float* Scr  = RB;                 // fdft partials: 496*16384 = 8.13M <= 8.39M

  unsigned short* Xb  = (unsigned short*)RB;
  unsigned short* Cb  = (unsigned short*)DD;
  unsigned short* Wb0 = (unsigned short*)UdFc;
  unsigned short* Wb1 = (unsigned short*)UdFc;

  const size_t BASE_FLOATS = 36421632ull;
  const size_t WT_FLOATS   = 25165824ull;
  if (ws_size < BASE_FLOATS * 4) return;
  const bool use_wt = ws_size >= (BASE_FLOATS + WT_FLOATS) * 4;
  uint32* W4lo = (uint32*)WT;                       // 16*262144 u32 = 4194304 floats
  uint32* W4hi = (uint32*)(WT + 4194304ull);
  uint32* W2b  = (uint32*)(WT + 8388608ull);
  unsigned short* AudP = (unsigned short*)(WT + 12582912ull);
  unsigned short* AusP = (unsigned short*)(WT + 13369344ull);

  // 1. bf16 converts + Lk0 GEMM (MFMA)
  k_cvt_x<<<dim3(4096), dim3(256), 0, stream>>>(x, Xb);
  k_cvt_gen<<<dim3(128), dim3(256), 0, stream>>>(Lk0_w, Wb0);
  k_gemm_bf16<<<dim3(128, 4), dim3(256), 0, stream>>>(Xb, Wb0, Lk0_b, V0);

  // 2. fused decomposition: levels 1-4, 5-8, 9-11
  k_decomp_tree<<<dim3(256, 4), dim3(256), 0, stream>>>(
      V0, ec_s, ec_d, DD, VD, 1, 4, 4096);
  k_decomp_tree<<<dim3(16, 4), dim3(256), 0, stream>>>(
      VD + 4ull * 3584 * 512, ec_s, ec_d, DD, VD, 5, 4, 256);
  // level-8 v arena base = 4*(4096 - (4096>>7)) = 4*4064
  k_decomp_tree<<<dim3(1, 4), dim3(256), 0, stream>>>(
      VD + 4ull * 4064 * 512, ec_s, ec_d, DD, VD, 9, 3, 16);

  // 3. T0 on v_11
  k_t0<<<dim3(2), dim3(256), 0, stream>>>(VD + (size_t)4 * 4092 * 512, T0_w, T0_b, RA);

  // 4. weight repack to planar bf16 [f][g]; no-LDS, barrier-free
  if (use_wt)
    k_transw6b<<<dim3(1024, 3), dim3(256), 0, stream>>>(
        Ar, Ai, Br, Bi, Cr, Ci, W4lo, W4hi, W2b);

  // 5. forward DFTs (chunk=64, 4-deep pipeline) -> partials, then
  //    deterministic reduction (no atomics anywhere -> replay-stable)
  k_fdft<<<dim3(68, 4, 2), dim3(256), 0, stream>>>(
      DD, VD, Scr, XDre, XDim, XVre, XVim);
  k_fdft_red<<<dim3(2560), dim3(256), 0, stream>>>(
      Scr, XDre, XDim, XVre, XVim);

  if (use_wt) {
    k_packA<<<dim3(384), dim3(256), 0, stream>>>(XDre, XDim, XVre, XVim, AudP, AusP);
    k_mixmm<<<dim3(16, 4, 4), dim3(256), 0, stream>>>(
        W4lo, W4hi, W2b, AudP, AusP, Part);
    k_reduce4<<<dim3((XPLANE + 255) / 256), dim3(256), 0, stream>>>(
        Part, UdFc, UsFc);
  } else {
    k_mix_fb<<<dim3(16, 4), dim3(512), 0, stream>>>(
        XDre, XDim, XVre, XVim, Ar, Ai, Br, Bi, Cr, Ci,
        UdFc, UsFc);
  }

  // 8. inverse DFTs into time-domain Ud/Us arenas
  k_idft<<<dim3(513, 4), dim3(256), 0, stream>>>(UdFc, UsFc, UdT, UsT);

  // 9. fused reconstruction: j=11..9 (RA->SA), j=8..5 (SA->SB), j=4..1 (SB->RB)
  k_recon_tree<<<dim3(1, 4), dim3(256), 0, stream>>>(
      RA, UdT, UsT, rc_e, rc_o, SA, 11, 3, 2, 2, 16);
  k_recon_tree<<<dim3(16, 4), dim3(256), 0, stream>>>(
      SA, UdT, UsT, rc_e, rc_o, SB, 8, 4, 1, 16, 256);
  k_recon_tree<<<dim3(256, 4), dim3(256), 0, stream>>>(
      SB, UdT, UsT, rc_e, rc_o, RB, 4, 4, 1, 256, 4096);

  // 10. Lk1 GEMM (MFMA)
  k_cvt_c<<<dim3(3072), dim3(256), 0, stream>>>(RB, Cb);
  k_cvt_gen<<<dim3(128), dim3(256), 0, stream>>>(Lk1_w, Wb1);
  k_gemm_bf16<<<dim3(96, 4), dim3(256), 0, stream>>>(Cb, Wb1, Lk1_b, out);
}

// Round 12
// 430.562 us; speedup vs baseline: 1.0146x; 1.0146x over previous
//
#include <hip/hip_runtime.h>

#define CKD 512
#define NROWS 44
#define XPLANE 360448  // 16*44*512

static __device__ __forceinline__ int imin(int a, int b) { return a < b ? a : b; }

typedef short bf16x8 __attribute__((ext_vector_type(8)));
typedef float f32x4 __attribute__((ext_vector_type(4)));
typedef unsigned int uint32;

// RNE float->bf16 pack of two floats into one u32 (lo = a, hi = b)
static __device__ __forceinline__ unsigned int pk2(float a, float b) {
  unsigned int ua = __float_as_uint(a), ub = __float_as_uint(b);
  ua = (ua + 0x7fffu + ((ua >> 16) & 1u)) >> 16;
  ub = (ub + 0x7fffu + ((ub >> 16) & 1u)) >> 16;
  return ua | (ub << 16);
}

static __device__ __forceinline__ uint32 ror16(uint32 q) { return (q >> 16) | (q << 16); }

static __device__ __forceinline__ bf16x8 mk_neghi(uint32 q0, uint32 q1, uint32 q2, uint32 q3) {
  union { uint32 u[4]; bf16x8 h; } t;
  t.u[0] = q0 ^ 0x80000000u; t.u[1] = q1 ^ 0x80000000u;
  t.u[2] = q2 ^ 0x80000000u; t.u[3] = q3 ^ 0x80000000u;
  return t.h;
}
static __device__ __forceinline__ bf16x8 mk_swap(uint32 q0, uint32 q1, uint32 q2, uint32 q3) {
  union { uint32 u[4]; bf16x8 h; } t;
  t.u[0] = ror16(q0); t.u[1] = ror16(q1); t.u[2] = ror16(q2); t.u[3] = ror16(q3);
  return t.h;
}

// ---------------------------------------------------------------------------
// Convert x (4,3072,512) fp32 -> Xb (4,4096,512) bf16 with wraparound pad
// ---------------------------------------------------------------------------
__global__ __launch_bounds__(256) void k_cvt_x(
    const float* __restrict__ src, unsigned short* __restrict__ dst)
{
  int g = blockIdx.x * 256 + threadIdx.x;      // 16384*64
  int row = g >> 6, c8 = (g & 63) << 3;
  int b = row >> 12, t = row & 4095;
  if (t >= 3072) t -= 3072;
  const float* s = src + ((size_t)(b * 3072 + t) << 9) + c8;
  float4 v0 = *(const float4*)s;
  float4 v1 = *(const float4*)(s + 4);
  uint4 o = make_uint4(pk2(v0.x, v0.y), pk2(v0.z, v0.w),
                       pk2(v1.x, v1.y), pk2(v1.z, v1.w));
  *(uint4*)(dst + ((size_t)row << 9) + c8) = o;
}

__global__ __launch_bounds__(256) void k_cvt_gen(
    const float* __restrict__ src, unsigned short* __restrict__ dst)
{
  int g = blockIdx.x * 256 + threadIdx.x;
  const float* s = src + ((size_t)g << 3);
  float4 v0 = *(const float4*)s;
  float4 v1 = *(const float4*)(s + 4);
  uint4 o = make_uint4(pk2(v0.x, v0.y), pk2(v0.z, v0.w),
                       pk2(v1.x, v1.y), pk2(v1.z, v1.w));
  *(uint4*)(dst + ((size_t)g << 3)) = o;
}

__global__ __launch_bounds__(256) void k_cvt_c(
    const float* __restrict__ src, unsigned short* __restrict__ dst)
{
  int g = blockIdx.x * 256 + threadIdx.x;      // 12288*64
  int row = g >> 6, c8 = (g & 63) << 3;
  int b = row / 3072, t = row - b * 3072;
  const float* s = src + ((size_t)((b << 12) + t) << 9) + c8;
  float4 v0 = *(const float4*)s;
  float4 v1 = *(const float4*)(s + 4);
  uint4 o = make_uint4(pk2(v0.x, v0.y), pk2(v0.z, v0.w),
                       pk2(v1.x, v1.y), pk2(v1.z, v1.w));
  *(uint4*)(dst + ((size_t)row << 9) + c8) = o;
}

// ---------------------------------------------------------------------------
// bf16 MFMA GEMM: Out[m][n] = sum_k A[m][k]*W[n][k] + bias[n], K=N=512
// ---------------------------------------------------------------------------
__global__ __launch_bounds__(256) void k_gemm_bf16(
    const unsigned short* __restrict__ A, const unsigned short* __restrict__ W,
    const float* __restrict__ bias, float* __restrict__ Out)
{
  __shared__ unsigned short As[128 * 40];
  __shared__ unsigned short Bs[128 * 40];
  const int tid = threadIdx.x;
  const int row = tid >> 1, half = tid & 1;
  const int bm0 = blockIdx.x << 7, bn0 = blockIdx.y << 7;
  const int wv = tid >> 6, l = tid & 63;
  const int wm0 = (wv & 1) << 6, wn0 = (wv >> 1) << 6;
  const int fr = l & 15, fq = l >> 4;

  const unsigned short* Ap = A + (size_t)(bm0 + row) * CKD + half * 16;
  const unsigned short* Wp = W + (size_t)(bn0 + row) * CKD + half * 16;

  f32x4 acc[4][4];
#pragma unroll
  for (int mt = 0; mt < 4; ++mt)
#pragma unroll
    for (int nt = 0; nt < 4; ++nt) {
      acc[mt][nt][0] = 0.f; acc[mt][nt][1] = 0.f;
      acc[mt][nt][2] = 0.f; acc[mt][nt][3] = 0.f;
    }

  for (int k0 = 0; k0 < CKD; k0 += 32) {
    uint4 av0 = *(const uint4*)(Ap + k0);
    uint4 av1 = *(const uint4*)(Ap + k0 + 8);
    uint4 bv0 = *(const uint4*)(Wp + k0);
    uint4 bv1 = *(const uint4*)(Wp + k0 + 8);
    __syncthreads();
    *(uint4*)&As[row * 40 + half * 16]     = av0;
    *(uint4*)&As[row * 40 + half * 16 + 8] = av1;
    *(uint4*)&Bs[row * 40 + half * 16]     = bv0;
    *(uint4*)&Bs[row * 40 + half * 16 + 8] = bv1;
    __syncthreads();
    bf16x8 af[4], bfr[4];
#pragma unroll
    for (int mt = 0; mt < 4; ++mt)
      af[mt] = *(const bf16x8*)&As[(wm0 + mt * 16 + fr) * 40 + fq * 8];
#pragma unroll
    for (int nt = 0; nt < 4; ++nt)
      bfr[nt] = *(const bf16x8*)&Bs[(wn0 + nt * 16 + fr) * 40 + fq * 8];
#pragma unroll
    for (int mt = 0; mt < 4; ++mt)
#pragma unroll
      for (int nt = 0; nt < 4; ++nt)
        acc[mt][nt] = __builtin_amdgcn_mfma_f32_16x16x32_bf16(
            af[mt], bfr[nt], acc[mt][nt], 0, 0, 0);
  }

#pragma unroll
  for (int nt = 0; nt < 4; ++nt) {
    int col = bn0 + wn0 + nt * 16 + fr;
    float bv = bias[col];
#pragma unroll
    for (int mt = 0; mt < 4; ++mt) {
      int r0 = bm0 + wm0 + mt * 16 + fq * 4;
#pragma unroll
      for (int rg = 0; rg < 4; ++rg)
        Out[(size_t)(r0 + rg) * CKD + col] = acc[mt][nt][rg] + bv;
    }
  }
}

// ---------------------------------------------------------------------------
// Fused decomposition tree: one block stages 16 input rows in LDS and emits
// NL levels (8,4,2,1 output rows) of d/v to the global arenas.
// grid = (pin/16, 4 batches). j0 = first level, pin = rows/batch of Vin.
// ---------------------------------------------------------------------------
__global__ __launch_bounds__(256) void k_decomp_tree(
    const float* __restrict__ Vin, const float* __restrict__ ec_s,
    const float* __restrict__ ec_d, float* __restrict__ DD,
    float* __restrict__ VD, int j0, int NL, int pin)
{
  __shared__ float Es[128], Ed[128];
  __shared__ float bufA[16 * 512];
  __shared__ float bufB[8 * 512];
  const int tid = threadIdx.x;
  if (tid < 128) Es[tid] = ec_s[tid];
  else Ed[tid - 128] = ec_d[tid - 128];
  const int b = blockIdx.y;
  const int t0 = blockIdx.x << 4;

  const float* src = Vin + ((size_t)b * pin + t0) * CKD;
  for (int q = tid; q < 16 * 128; q += 256) {
    int rr = q >> 7, c4 = (q & 127) << 2;
    *(float4*)&bufA[rr * 512 + c4] = *(const float4*)(src + (size_t)rr * CKD + c4);
  }
  __syncthreads();

  float* rd = bufA;
  float* wr = bufB;
  for (int lv = 0; lv < NL; ++lv) {
    const int j = j0 + lv;
    const int Lout = 4096 >> j;
    const int rows = 8 >> lv;
    const int sb = t0 >> (lv + 1);
    const size_t base = 4ull * (4096 - (4096 >> (j - 1))) * CKD;
    float* Dp = DD + base;
    float* Vp = VD + base;
    for (int task = tid; task < rows * 64; task += 256) {
      int s = task >> 6, c = task & 63;
      const float* r0p = rd + (2 * s) * 512 + (c << 3);
      float a[16];
      float4 v0 = *(const float4*)r0p;
      float4 v1 = *(const float4*)(r0p + 4);
      float4 v2 = *(const float4*)(r0p + 512);
      float4 v3 = *(const float4*)(r0p + 516);
      a[0]=v0.x; a[1]=v0.y; a[2]=v0.z; a[3]=v0.w; a[4]=v1.x; a[5]=v1.y; a[6]=v1.z; a[7]=v1.w;
      a[8]=v2.x; a[9]=v2.y; a[10]=v2.z; a[11]=v2.w; a[12]=v3.x; a[13]=v3.y; a[14]=v3.z; a[15]=v3.w;
      float dv[8] = {}, vv[8] = {};
#pragma unroll
      for (int m = 0; m < 16; ++m)
#pragma unroll
        for (int k = 0; k < 8; ++k) {
          dv[k] += a[m] * Ed[m * 8 + k];
          vv[k] += a[m] * Es[m * 8 + k];
        }
      size_t orow = ((size_t)b * Lout + sb + s) * CKD + (c << 3);
      *(float4*)(Dp + orow)     = make_float4(dv[0], dv[1], dv[2], dv[3]);
      *(float4*)(Dp + orow + 4) = make_float4(dv[4], dv[5], dv[6], dv[7]);
      *(float4*)(Vp + orow)     = make_float4(vv[0], vv[1], vv[2], vv[3]);
      *(float4*)(Vp + orow + 4) = make_float4(vv[4], vv[5], vv[6], vv[7]);
      if (lv + 1 < NL) {
        float* wp = wr + s * 512 + (c << 3);
        *(float4*)wp       = make_float4(vv[0], vv[1], vv[2], vv[3]);
        *(float4*)(wp + 4) = make_float4(vv[4], vv[5], vv[6], vv[7]);
      }
    }
    __syncthreads();
    float* t = rd; rd = wr; wr = t;
  }
}

// ---------------------------------------------------------------------------
// T0
// ---------------------------------------------------------------------------
__global__ __launch_bounds__(256) void k_t0(
    const float* __restrict__ Vin, const float* __restrict__ T0w,
    const float* __restrict__ T0b, float* __restrict__ Out)
{
  int g = blockIdx.x * 256 + threadIdx.x;
  if (g >= 4 * 2 * 64) return;
  int c = g & 63;
  int t = (g >> 6) & 1;
  int b = g >> 7;
  const float* src = Vin + ((size_t)(b * 2 + t)) * CKD + (c << 3);
  float a[8];
  float4 v0 = *(const float4*)src;
  float4 v1 = *(const float4*)(src + 4);
  a[0]=v0.x; a[1]=v0.y; a[2]=v0.z; a[3]=v0.w; a[4]=v1.x; a[5]=v1.y; a[6]=v1.z; a[7]=v1.w;
  float o[8];
#pragma unroll
  for (int ko = 0; ko < 8; ++ko) {
    float sum = T0b[ko];
#pragma unroll
    for (int k = 0; k < 8; ++k) sum += a[k] * T0w[ko * 8 + k];
    o[ko] = sum;
  }
  float* dst = Out + ((size_t)(b * 2 + t)) * CKD + (c << 3);
  *(float4*)dst       = make_float4(o[0], o[1], o[2], o[3]);
  *(float4*)(dst + 4) = make_float4(o[4], o[5], o[6], o[7]);
}

// ---------------------------------------------------------------------------
// Forward truncated DFT, t-chunk = 64, 4-deep software pipeline.
// Multi-chunk levels (L>64) write per-chunk partials to Scr (deterministic,
// reduced by k_fdft_red); single-chunk levels store directly.
// NO atomics -> bit-identical on every launch.
// ---------------------------------------------------------------------------
__global__ __launch_bounds__(256) void k_fdft(
    const float* __restrict__ DD, const float* __restrict__ VD,
    float* __restrict__ Scr,
    float* __restrict__ XDre, float* __restrict__ XDim,
    float* __restrict__ XVre, float* __restrict__ XVim)
{
  __shared__ float2 tw[1024];  // [f][64]
  int bx = blockIdx.x, j = 1;
  for (;;) {
    int c = (4096 >> j) >> 6; if (c < 1) c = 1;
    if (bx < c) break;
    bx -= c; ++j;
  }
  const int L = 4096 >> j;
  const int t0 = bx << 6;
  const int tcnt = imin(64, L - t0);
  const bool multi = (L > 64);
  const int b = blockIdx.y;
  const int z = blockIdx.z;
  const int r = (j - 1) * 4 + b;
  const float* src = (z ? VD : DD) +
      ((size_t)(4 * (4096 - (4096 >> (j - 1))) + b * L)) * CKD;
  float* dre = z ? XVre : XDre;
  float* dim_ = z ? XVim : XDim;

  for (int idx = threadIdx.x; idx < 1024; idx += 256) {
    int ff = idx >> 6, tl = idx & 63;
    int t = t0 + tl;
    int m = (2 * ff * t) & (2 * L - 1);
    float xang = (float)m / (float)L;
    tw[idx] = make_float2(cospif(xang), sinpif(xang));
  }
  __syncthreads();

  float ar[16][2] = {};
  float ai[16][2] = {};
  const float* sp = src + (size_t)t0 * CKD + (threadIdx.x << 1);

  if (tcnt >= 4) {
    // tcnt is one of {4,8,16,32,64} here -> always a multiple of 4
    float2 q0 = *(const float2*)(sp + 0 * (size_t)CKD);
    float2 q1 = *(const float2*)(sp + 1 * (size_t)CKD);
    float2 q2 = *(const float2*)(sp + 2 * (size_t)CKD);
    float2 q3 = *(const float2*)(sp + 3 * (size_t)CKD);
    int tl = 0;
    for (;;) {
      float2 x0 = q0, x1 = q1, x2 = q2, x3 = q3;
      const int nx = tl + 4;
      if (nx < tcnt) {
        q0 = *(const float2*)(sp + (size_t)(nx + 0) * CKD);
        q1 = *(const float2*)(sp + (size_t)(nx + 1) * CKD);
        q2 = *(const float2*)(sp + (size_t)(nx + 2) * CKD);
        q3 = *(const float2*)(sp + (size_t)(nx + 3) * CKD);
      }
#pragma unroll
      for (int ff = 0; ff < 16; ++ff) {
        float2 c0 = tw[(ff << 6) + tl + 0];
        float2 c1 = tw[(ff << 6) + tl + 1];
        float2 c2 = tw[(ff << 6) + tl + 2];
        float2 c3 = tw[(ff << 6) + tl + 3];
        ar[ff][0] += x0.x * c0.x; ar[ff][1] += x0.y * c0.x;
        ai[ff][0] -= x0.x * c0.y; ai[ff][1] -= x0.y * c0.y;
        ar[ff][0] += x1.x * c1.x; ar[ff][1] += x1.y * c1.x;
        ai[ff][0] -= x1.x * c1.y; ai[ff][1] -= x1.y * c1.y;
        ar[ff][0] += x2.x * c2.x; ar[ff][1] += x2.y * c2.x;
        ai[ff][0] -= x2.x * c2.y; ai[ff][1] -= x2.y * c2.y;
        ar[ff][0] += x3.x * c3.x; ar[ff][1] += x3.y * c3.x;
        ai[ff][0] -= x3.x * c3.y; ai[ff][1] -= x3.y * c3.y;
      }
      tl = nx;
      if (tl >= tcnt) break;
    }
  } else {
    // deepest level: tcnt == 2
    for (int tl = 0; tl < tcnt; ++tl) {
      float2 xv = *(const float2*)(sp + (size_t)tl * CKD);
#pragma unroll
      for (int ff = 0; ff < 16; ++ff) {
        float2 cs = tw[(ff << 6) + tl];
        ar[ff][0] += xv.x * cs.x; ar[ff][1] += xv.y * cs.x;
        ai[ff][0] -= xv.x * cs.y; ai[ff][1] -= xv.y * cs.y;
      }
    }
  }

  const int i0 = threadIdx.x << 1;
  if (multi) {
    // partial slot: (chunk, b, z); chunk = chunks-before-level-j + bx
    const int chunk = 64 - (64 >> (j - 1)) + bx;
    float* S = Scr + ((size_t)((((chunk << 2) + b) << 1) + z)) * 16384;
#pragma unroll
    for (int ff = 0; ff < 16; ++ff) {
      *(float2*)(S + (ff << 10) + i0)       = make_float2(ar[ff][0], ar[ff][1]);
      *(float2*)(S + (ff << 10) + 512 + i0) = make_float2(ai[ff][0], ai[ff][1]);
    }
  } else {
#pragma unroll
    for (int ff = 0; ff < 16; ++ff) {
      size_t bidx = ((size_t)ff * NROWS + r) * CKD + i0;
      *(float2*)(dre + bidx)  = make_float2(ar[ff][0], ar[ff][1]);
      *(float2*)(dim_ + bidx) = make_float2(ai[ff][0], ai[ff][1]);
    }
  }
}

// ---------------------------------------------------------------------------
// Deterministic reduction of per-chunk DFT partials -> XD*/XV* rows 0..19.
// One thread per (r<20, z, ff, part, i); sums chunks in fixed order.
// ---------------------------------------------------------------------------
__global__ __launch_bounds__(256) void k_fdft_red(
    const float* __restrict__ Scr,
    float* __restrict__ XDre, float* __restrict__ XDim,
    float* __restrict__ XVre, float* __restrict__ XVim)
{
  int g = blockIdx.x * 256 + threadIdx.x;   // 20*2*16*2*512 = 655360
  int i = g & 511;
  int part = (g >> 9) & 1;
  int ff = (g >> 10) & 15;
  int z = (g >> 14) & 1;
  int r = g >> 15;            // 0..19
  int jidx = r >> 2;          // level-1: 0..4
  int b = r & 3;
  int c = 32 >> jidx;         // chunks in this level: 32,16,8,4,2
  int cbase = 64 - (64 >> jidx);
  const float* base = Scr
      + ((size_t)((((cbase << 2) + b) << 1) + z)) * 16384
      + (ff << 10) + (part << 9) + i;
  const size_t STR = 8ull * 16384;  // slot stride between consecutive chunks
  float s0 = 0.f, s1 = 0.f, s2 = 0.f, s3 = 0.f;
  int k = 0;
  for (; k + 4 <= c; k += 4) {
    s0 += base[(size_t)(k + 0) * STR];
    s1 += base[(size_t)(k + 1) * STR];
    s2 += base[(size_t)(k + 2) * STR];
    s3 += base[(size_t)(k + 3) * STR];
  }
  for (; k < c; ++k) s0 += base[(size_t)k * STR];
  float s = (s0 + s1) + (s2 + s3);
  float* dst = part ? (z ? XVim : XDim) : (z ? XVre : XDre);
  dst[((size_t)ff * NROWS + r) * CKD + i] = s;
}

// ---------------------------------------------------------------------------
// Weight repack to packed bf16, planar outputs W4lo/W4hi/W2b ([f][g] u32).
// Round-11 lesson: VGPR=28 showed the compiler serializes 8-load threads
// into ~2-in-flight batches -> 2.2 TB/s latency cap. Fix: one dependence-
// free (re,im) float4 pair per thread (t = g*4+fg), lanes perfectly
// contiguous (100% line density/instr), 4x threads -> full-occupancy TLP.
// grid = (4096, 3): blockIdx.y picks the (re,im,dst) phase.
// ---------------------------------------------------------------------------
__global__ __launch_bounds__(256) void k_transw6b(
    const float* __restrict__ sAr, const float* __restrict__ sAi,
    const float* __restrict__ sBr, const float* __restrict__ sBi,
    const float* __restrict__ sCr, const float* __restrict__ sCi,
    uint32* __restrict__ W4lo, uint32* __restrict__ W4hi,
    uint32* __restrict__ W2b)
{
  const int t = (blockIdx.x << 8) + threadIdx.x;   // 0 .. 1048575 per phase
  const int p = blockIdx.y;
  const int g = t >> 2, fg = t & 3;
  const float* re = (p == 0) ? sAr : (p == 1) ? sBr : sCr;
  const float* im = (p == 0) ? sAi : (p == 1) ? sBi : sCi;
  uint32* dst = (p == 0) ? W4lo : (p == 1) ? W4hi : W2b;

  const size_t base = (size_t)g * 16 + (fg << 2);
  float4 r = *(const float4*)(re + base);
  float4 i = *(const float4*)(im + base);
  const int f0 = fg << 2;
  dst[((size_t)(f0 + 0) << 18) + g] = pk2(r.x, i.x);
  dst[((size_t)(f0 + 1) << 18) + g] = pk2(r.y, i.y);
  dst[((size_t)(f0 + 2) << 18) + g] = pk2(r.z, i.z);
  dst[((size_t)(f0 + 3) << 18) + g] = pk2(r.w, i.w);
}

// ---------------------------------------------------------------------------
// Pack spectral X -> bf16 MFMA A-matrices
// ---------------------------------------------------------------------------
__global__ __launch_bounds__(256) void k_packA(
    const float* __restrict__ XDre, const float* __restrict__ XDim,
    const float* __restrict__ XVre, const float* __restrict__ XVim,
    unsigned short* __restrict__ Aud, unsigned short* __restrict__ Aus)
{
  int g = blockIdx.x * 256 + threadIdx.x;   // 16 * 48 * 128
  int f = g / 6144;
  int rem = g - f * 6144;
  int r = rem >> 7, iq = rem & 127;
  uint4 w0 = make_uint4(0,0,0,0), w1 = w0, wu = w0;
  if (r < NROWS) {
    size_t base = ((size_t)f * NROWS + r) * CKD + (iq << 2);
    float4 dre = *(const float4*)(XDre + base);
    float4 dim_ = *(const float4*)(XDim + base);
    float4 vre = *(const float4*)(XVre + base);
    float4 vim = *(const float4*)(XVim + base);
    w0 = make_uint4(pk2(dre.x, dim_.x), pk2(vre.x, vim.x),
                    pk2(dre.y, dim_.y), pk2(vre.y, vim.y));
    w1 = make_uint4(pk2(dre.z, dim_.z), pk2(vre.z, vim.z),
                    pk2(dre.w, dim_.w), pk2(vre.w, vim.w));
    wu = make_uint4(pk2(dre.x, dim_.x), pk2(dre.y, dim_.y),
                    pk2(dre.z, dim_.z), pk2(dre.w, dim_.w));
  }
  size_t du = ((size_t)f * 48 + r) * 2048 + (iq << 4);
  *(uint4*)(Aud + du)     = w0;
  *(uint4*)(Aud + du + 8) = w1;
  *(uint4*)(Aus + ((size_t)f * 48 + r) * 1024 + (iq << 3)) = wu;
}

// ---------------------------------------------------------------------------
// MFMA channel mix; partials -> Part[is][plane][f*44+r][o]
// W4 planar (W4lo/W4hi): stage two 8B loads, reassemble into sBud.
// ---------------------------------------------------------------------------
__global__ __launch_bounds__(256) void k_mixmm(
    const uint32* __restrict__ W4lo, const uint32* __restrict__ W4hi,
    const uint32* __restrict__ W2b,
    const unsigned short* __restrict__ Aud, const unsigned short* __restrict__ Aus,
    float* __restrict__ Part)
{
  __shared__ __attribute__((aligned(16))) uint2 sBud[16 * 130];
  __shared__ __attribute__((aligned(16))) uint32 sBus[16 * 132];
  __shared__ __attribute__((aligned(16))) unsigned short sAud[48 * 72];
  __shared__ __attribute__((aligned(16))) unsigned short sAus[48 * 40];

  const int f = blockIdx.x;
  const int o0 = blockIdx.y << 7;
  const int is = blockIdx.z;
  const int i0 = is << 7;
  const int tid = threadIdx.x;
  const int w = tid >> 6, l = tid & 63;
  const int fr = l & 15, fq = l >> 4;
  const int ow0 = w << 5;

  const uint32* gWlo = W4lo + ((size_t)f << 18);
  const uint32* gWhi = W4hi + ((size_t)f << 18);
  const uint32* gW2 = W2b + ((size_t)f << 18);
  const unsigned short* gAud = Aud + (size_t)f * 48 * 2048;
  const unsigned short* gAus = Aus + (size_t)f * 48 * 1024;

  f32x4 aUd[3][2][2], aUs[3][2][2];
#pragma unroll
  for (int m = 0; m < 3; ++m)
#pragma unroll
    for (int ot = 0; ot < 2; ++ot)
#pragma unroll
      for (int cp = 0; cp < 2; ++cp) {
        aUd[m][ot][cp][0]=0.f; aUd[m][ot][cp][1]=0.f; aUd[m][ot][cp][2]=0.f; aUd[m][ot][cp][3]=0.f;
        aUs[m][ot][cp][0]=0.f; aUs[m][ot][cp][1]=0.f; aUs[m][ot][cp][2]=0.f; aUs[m][ot][cp][3]=0.f;
      }

  for (int ic = 0; ic < 8; ++ic) {
    const int ig = i0 + (ic << 4);
    __syncthreads();
#pragma unroll
    for (int n = 0; n < 4; ++n) {
      int q = tid + (n << 8);
      int il = q >> 6, op = (q & 63) << 1;
      size_t gi = (size_t)(ig + il) * 512 + o0 + op;
      uint2 lo2 = *(const uint2*)(gWlo + gi);
      uint2 hi2 = *(const uint2*)(gWhi + gi);
      *(uint4*)&sBud[il * 130 + op] = make_uint4(lo2.x, hi2.x, lo2.y, hi2.y);
    }
#pragma unroll
    for (int n = 0; n < 2; ++n) {
      int q = tid + (n << 8);
      int il = q >> 5, oq = (q & 31) << 2;
      uint4 v = *(const uint4*)(gW2 + (size_t)(ig + il) * 512 + o0 + oq);
      *(uint4*)&sBus[il * 132 + oq] = v;
    }
    {
      int q = tid;
      int m = q >> 3, k8 = (q & 7) << 3;
      uint4 v = *(const uint4*)(gAud + (size_t)m * 2048 + (is << 9) + (ic << 6) + k8);
      *(uint4*)&sAud[m * 72 + k8] = v;
      q = tid + 256;
      if (q < 384) {
        m = q >> 3; k8 = (q & 7) << 3;
        uint4 v2 = *(const uint4*)(gAud + (size_t)m * 2048 + (is << 9) + (ic << 6) + k8);
        *(uint4*)&sAud[m * 72 + k8] = v2;
      }
    }
    if (tid < 192) {
      int m = tid >> 2, k8 = (tid & 3) << 3;
      uint4 v = *(const uint4*)(gAus + (size_t)m * 1024 + (is << 8) + (ic << 5) + k8);
      *(uint4*)&sAus[m * 40 + k8] = v;
    }
    __syncthreads();

#pragma unroll
    for (int ks = 0; ks < 2; ++ks) {
      bf16x8 af[3];
#pragma unroll
      for (int m = 0; m < 3; ++m)
        af[m] = *(const bf16x8*)&sAud[(m * 16 + fr) * 72 + (ks << 5) + (fq << 3)];
#pragma unroll
      for (int ot = 0; ot < 2; ++ot) {
        int ol = ow0 + (ot << 4) + fr;
        int il = (ks << 3) + (fq << 1);
        uint2 qa = sBud[il * 130 + ol];
        uint2 qb = sBud[(il + 1) * 130 + ol];
        bf16x8 b0 = mk_neghi(qa.x, qa.y, qb.x, qb.y);
        bf16x8 b1 = mk_swap(qa.x, qa.y, qb.x, qb.y);
#pragma unroll
        for (int m = 0; m < 3; ++m) {
          aUd[m][ot][0] = __builtin_amdgcn_mfma_f32_16x16x32_bf16(af[m], b0, aUd[m][ot][0], 0, 0, 0);
          aUd[m][ot][1] = __builtin_amdgcn_mfma_f32_16x16x32_bf16(af[m], b1, aUd[m][ot][1], 0, 0, 0);
        }
      }
    }
    {
      bf16x8 af[3];
#pragma unroll
      for (int m = 0; m < 3; ++m)
        af[m] = *(const bf16x8*)&sAus[(m * 16 + fr) * 40 + (fq << 3)];
#pragma unroll
      for (int ot = 0; ot < 2; ++ot) {
        int ol = ow0 + (ot << 4) + fr;
        int il = fq << 2;
        uint32 q0 = sBus[(il + 0) * 132 + ol];
        uint32 q1 = sBus[(il + 1) * 132 + ol];
        uint32 q2 = sBus[(il + 2) * 132 + ol];
        uint32 q3 = sBus[(il + 3) * 132 + ol];
        bf16x8 b0 = mk_neghi(q0, q1, q2, q3);
        bf16x8 b1 = mk_swap(q0, q1, q2, q3);
#pragma unroll
        for (int m = 0; m < 3; ++m) {
          aUs[m][ot][0] = __builtin_amdgcn_mfma_f32_16x16x32_bf16(af[m], b0, aUs[m][ot][0], 0, 0, 0);
          aUs[m][ot][1] = __builtin_amdgcn_mfma_f32_16x16x32_bf16(af[m], b1, aUs[m][ot][1], 0, 0, 0);
        }
      }
    }
  }

  float* P = Part + (size_t)is * 4 * XPLANE;
#pragma unroll
  for (int m = 0; m < 3; ++m) {
#pragma unroll
    for (int reg = 0; reg < 4; ++reg) {
      int r = m * 16 + (fq << 2) + reg;
      if (r < NROWS) {
        size_t rb = ((size_t)f * NROWS + r) * CKD;
#pragma unroll
        for (int ot = 0; ot < 2; ++ot) {
          int col = o0 + ow0 + (ot << 4) + fr;
          P[0 * XPLANE + rb + col] = aUd[m][ot][0][reg];
          P[1 * XPLANE + rb + col] = aUd[m][ot][1][reg];
          P[2 * XPLANE + rb + col] = aUs[m][ot][0][reg];
          P[3 * XPLANE + rb + col] = aUs[m][ot][1][reg];
        }
      }
    }
  }
}

// ---------------------------------------------------------------------------
// Reduce 4 i-split partials -> interleaved complex spectral arrays:
// UdFc/UsFc layout [row][i][re|im], row = f*NROWS + r (1024 floats per row).
// ---------------------------------------------------------------------------
__global__ __launch_bounds__(256) void k_reduce4(
    const float* __restrict__ Part,
    float* __restrict__ UdFc, float* __restrict__ UsFc)
{
  int idx = blockIdx.x * 256 + threadIdx.x;
  if (idx >= XPLANE) return;
  float s0 = 0.f, s1 = 0.f, s2 = 0.f, s3 = 0.f;
#pragma unroll
  for (int is = 0; is < 4; ++is) {
    const float* p = Part + (size_t)is * 4 * XPLANE;
    s0 += p[0 * XPLANE + idx];
    s1 += p[1 * XPLANE + idx];
    s2 += p[2 * XPLANE + idx];
    s3 += p[3 * XPLANE + idx];
  }
  int row = idx >> 9, i = idx & 511;
  size_t base = ((size_t)row << 10) + (i << 1);
  *(float2*)(UdFc + base) = make_float2(s0, s1);
  *(float2*)(UsFc + base) = make_float2(s2, s3);
}

// ---------------------------------------------------------------------------
// Fallback scalar mix (workspace too small for repack arenas); writes the
// same interleaved UdFc/UsFc layout.
// ---------------------------------------------------------------------------
__global__ __launch_bounds__(512) void k_mix_fb(
    const float* __restrict__ XDre, const float* __restrict__ XDim,
    const float* __restrict__ XVre, const float* __restrict__ XVim,
    const float* __restrict__ war, const float* __restrict__ wai,
    const float* __restrict__ wbr, const float* __restrict__ wbi,
    const float* __restrict__ wcr, const float* __restrict__ wci,
    float* __restrict__ UdFc, float* __restrict__ UsFc)
{
  const int f = blockIdx.x;
  const int ot = blockIdx.y;
  const int lane = threadIdx.x & 63;
  const int rg = threadIdx.x >> 6;
  const int rbase = (rg < 4) ? rg * 6 : 24 + (rg - 4) * 5;
  const int rcnt = (rg < 4) ? 6 : 5;
  const int o0 = (ot << 7) + lane;
  __shared__ float4 sx[NROWS * 64];
  float udr[6][2] = {}, udi[6][2] = {}, usr[6][2] = {}, usi[6][2] = {};
  for (int i0 = 0; i0 < 512; i0 += 64) {
    __syncthreads();
    for (int idx = threadIdx.x; idx < NROWS * 64; idx += 512) {
      int r = idx >> 6, il = idx & 63;
      size_t xb = ((size_t)f * NROWS + r) * CKD + i0 + il;
      sx[idx] = make_float4(XDre[xb], XDim[xb], XVre[xb], XVim[xb]);
    }
    __syncthreads();
    for (int ii = 0; ii < 64; ++ii) {
      int i = i0 + ii;
      size_t wo = ((((size_t)i << 9) + o0) << 4) + f;
      float4 wa0 = make_float4(war[wo], wai[wo], wbr[wo], wbi[wo]);
      float2 wc0 = make_float2(wcr[wo], wci[wo]);
      size_t w1 = wo + (64u << 4);
      float4 wa1 = make_float4(war[w1], wai[w1], wbr[w1], wbi[w1]);
      float2 wc1 = make_float2(wcr[w1], wci[w1]);
#pragma unroll
      for (int rr = 0; rr < 6; ++rr) {
        if (rr < rcnt) {
          float4 xv = sx[((rbase + rr) << 6) + ii];
          udr[rr][0] += xv.x * wa0.x - xv.y * wa0.y + xv.z * wa0.z - xv.w * wa0.w;
          udi[rr][0] += xv.x * wa0.y + xv.y * wa0.x + xv.z * wa0.w + xv.w * wa0.z;
          usr[rr][0] += xv.x * wc0.x - xv.y * wc0.y;
          usi[rr][0] += xv.x * wc0.y + xv.y * wc0.x;
          udr[rr][1] += xv.x * wa1.x - xv.y * wa1.y + xv.z * wa1.z - xv.w * wa1.w;
          udi[rr][1] += xv.x * wa1.y + xv.y * wa1.x + xv.z * wa1.w + xv.w * wa1.z;
          usr[rr][1] += xv.x * wc1.x - xv.y * wc1.y;
          usi[rr][1] += xv.x * wc1.y + xv.y * wc1.x;
        }
      }
    }
  }
#pragma unroll
  for (int rr = 0; rr < 6; ++rr) {
    if (rr < rcnt) {
      size_t base = ((size_t)(f * NROWS + rbase + rr)) << 10;
      *(float2*)(UdFc + base + (o0 << 1))        = make_float2(udr[rr][0], udi[rr][0]);
      *(float2*)(UdFc + base + ((o0 + 64) << 1)) = make_float2(udr[rr][1], udi[rr][1]);
      *(float2*)(UsFc + base + (o0 << 1))        = make_float2(usr[rr][0], usi[rr][0]);
      *(float2*)(UsFc + base + ((o0 + 64) << 1)) = make_float2(usr[rr][1], usi[rr][1]);
    }
  }
}

// ---------------------------------------------------------------------------
// Inverse truncated DFT. Interleaved UdFc/UsFc ([row][i][re|im]) float4
// loads. All accumulator indices compile-time constant (SROA -> VGPRs).
// ---------------------------------------------------------------------------
__global__ __launch_bounds__(256) void k_idft(
    const float* __restrict__ UdFc, const float* __restrict__ UsFc,
    float* __restrict__ UdT, float* __restrict__ UsT)
{
  __shared__ float2 tw[128];  // [f][8]
  int bx = blockIdx.x, j = 1;
  for (;;) {
    int c = (4096 >> j) >> 3; if (c < 1) c = 1;
    if (bx < c) break;
    bx -= c; ++j;
  }
  const int L = 4096 >> j;
  const int l = imin(16, (L >> 1) + 1);
  const int t0 = bx << 3;
  const int b = blockIdx.y;
  const int r = (j - 1) * 4 + b;
  if (threadIdx.x < 128) {
    int ff = threadIdx.x >> 3, tl = threadIdx.x & 7;
    int t = t0 + tl;
    int m = (2 * ff * t) & (2 * L - 1);
    float xang = (float)m / (float)L;
    float wgt = (ff == 0 || 2 * ff == L) ? 1.0f : 2.0f;
    float sc = wgt / (float)L;
    tw[threadIdx.x] = make_float2(cospif(xang) * sc, sinpif(xang) * sc);
  }
  __syncthreads();
  const size_t FS = (size_t)NROWS * 1024;  // stride between ff planes
  const float* pU = UdFc + ((size_t)r << 10) + (threadIdx.x << 2);
  const float* pS = UsFc + ((size_t)r << 10) + (threadIdx.x << 2);

  float2 ud[8], us[8];
#pragma unroll
  for (int tl = 0; tl < 8; ++tl) { ud[tl] = make_float2(0.f, 0.f); us[tl] = make_float2(0.f, 0.f); }

  for (int ff = 0; ff < l; ++ff) {
    float4 uv = *(const float4*)(pU + (size_t)ff * FS);
    float4 sv = *(const float4*)(pS + (size_t)ff * FS);
#pragma unroll
    for (int tl = 0; tl < 8; ++tl) {
      float2 cs = tw[(ff << 3) + tl];
      ud[tl].x += uv.x * cs.x - uv.y * cs.y;
      ud[tl].y += uv.z * cs.x - uv.w * cs.y;
      us[tl].x += sv.x * cs.x - sv.y * cs.y;
      us[tl].y += sv.z * cs.x - sv.w * cs.y;
    }
  }

  const int tmax = imin(8, L - t0);   // <8 only for the 2 deepest levels
  const int o = threadIdx.x << 1;
  size_t obase = ((size_t)(4 * (4096 - (4096 >> (j - 1))) + b * L + t0)) * CKD + o;
#pragma unroll
  for (int tl = 0; tl < 8; ++tl) {    // constant tl -> SROA keeps ud/us in VGPRs
    if (tl < tmax) {
      *(float2*)(UdT + obase + (size_t)tl * CKD) = ud[tl];
      *(float2*)(UsT + obase + (size_t)tl * CKD) = us[tl];
    }
  }
}

// ---------------------------------------------------------------------------
// Fused reconstruction tree: block loads ir input rows, expands NL levels in
// LDS (intermediate v never hits global), writes ir<<NL rows to Vout.
// grid = (LcIn/ir, 4). Levels processed: j0, j0-1, ..., j0-NL+1.
// LDS: asymmetric ping-pong buffers (16-row + 8-row = 48 KB, was 64 KB)
// -> 3 blocks/CU instead of 2. Start buffer chosen by NL parity so the
// final 16-row stage always lands in the big buffer.
// ---------------------------------------------------------------------------
__global__ __launch_bounds__(256) void k_recon_tree(
    const float* __restrict__ Vin, const float* __restrict__ UdT,
    const float* __restrict__ UsT, const float* __restrict__ rc_e,
    const float* __restrict__ rc_o, float* __restrict__ Vout,
    int j0, int NL, int ir, int pin, int pout)
{
  __shared__ float Re[128], Ro[128];
  __shared__ float bufL[16 * 512];
  __shared__ float bufS[8 * 512];
  const int tid = threadIdx.x;
  if (tid < 128) Re[tid] = rc_e[tid];
  else Ro[tid - 128] = rc_o[tid - 128];
  const int b = blockIdx.y;
  const int r0 = blockIdx.x * ir;

  float* rd = (NL & 1) ? bufS : bufL;
  float* wr = (NL & 1) ? bufL : bufS;

  for (int q = tid; q < ir * 128; q += 256) {
    int rr = q >> 7, c4 = (q & 127) << 2;
    *(float4*)&rd[rr * 512 + c4] =
        *(const float4*)(Vin + ((size_t)b * pin + r0 + rr) * CKD + c4);
  }
  __syncthreads();

  int rows = ir;
  for (int m = 0; m < NL; ++m) {
    const int j = j0 - m;
    const int Lc = 4096 >> j;
    const size_t ab = 4ull * (4096 - (4096 >> (j - 1))) * CKD;
    const int g0 = r0 << m;
    for (int task = tid; task < rows * 64; task += 256) {
      int s = task >> 6, c = task & 63;
      size_t arow = ab + ((size_t)b * Lc + g0 + s) * CKD + (c << 3);
      const float* vp = rd + s * 512 + (c << 3);
      float a[16];
      {
        float4 t0_ = *(const float4*)vp;
        float4 t1_ = *(const float4*)(vp + 4);
        float4 u0 = *(const float4*)(UsT + arow);
        float4 u1 = *(const float4*)(UsT + arow + 4);
        a[0]=t0_.x+u0.x; a[1]=t0_.y+u0.y; a[2]=t0_.z+u0.z; a[3]=t0_.w+u0.w;
        a[4]=t1_.x+u1.x; a[5]=t1_.y+u1.y; a[6]=t1_.z+u1.z; a[7]=t1_.w+u1.w;
        float4 d0 = *(const float4*)(UdT + arow);
        float4 d1 = *(const float4*)(UdT + arow + 4);
        a[8]=d0.x; a[9]=d0.y; a[10]=d0.z; a[11]=d0.w;
        a[12]=d1.x; a[13]=d1.y; a[14]=d1.z; a[15]=d1.w;
      }
      float xe[8] = {}, xo[8] = {};
#pragma unroll
      for (int mm = 0; mm < 16; ++mm)
#pragma unroll
        for (int k = 0; k < 8; ++k) {
          xe[k] += a[mm] * Re[mm * 8 + k];
          xo[k] += a[mm] * Ro[mm * 8 + k];
        }
      float* we = wr + (2 * s) * 512 + (c << 3);
      *(float4*)we         = make_float4(xe[0], xe[1], xe[2], xe[3]);
      *(float4*)(we + 4)   = make_float4(xe[4], xe[5], xe[6], xe[7]);
      *(float4*)(we + 512) = make_float4(xo[0], xo[1], xo[2], xo[3]);
      *(float4*)(we + 516) = make_float4(xo[4], xo[5], xo[6], xo[7]);
    }
    __syncthreads();
    float* t = rd; rd = wr; wr = t;
    rows <<= 1;
  }

  for (int q = tid; q < rows * 128; q += 256) {
    int rr = q >> 7, c4 = (q & 127) << 2;
    *(float4*)(Vout + ((size_t)b * pout + (r0 << NL) + rr) * CKD + c4) =
        *(const float4*)&rd[rr * 512 + c4];
  }
}

// ---------------------------------------------------------------------------
extern "C" void kernel_launch(void* const* d_in, const int* in_sizes, int n_in,
                              void* d_out, int out_size, void* d_ws, size_t ws_size,
                              hipStream_t stream)
{
  const float* x     = (const float*)d_in[0];
  const float* Lk0_w = (const float*)d_in[1];
  const float* Lk0_b = (const float*)d_in[2];
  const float* Lk1_w = (const float*)d_in[3];
  const float* Lk1_b = (const float*)d_in[4];
  const float* T0_w  = (const float*)d_in[5];
  const float* T0_b  = (const float*)d_in[6];
  const float* Ar = (const float*)d_in[7];
  const float* Ai = (const float*)d_in[8];
  const float* Br = (const float*)d_in[9];
  const float* Bi = (const float*)d_in[10];
  const float* Cr = (const float*)d_in[11];
  const float* Ci = (const float*)d_in[12];
  const float* ec_s = (const float*)d_in[13];
  const float* ec_d = (const float*)d_in[14];
  const float* rc_e = (const float*)d_in[15];
  const float* rc_o = (const float*)d_in[16];
  float* out = (float*)d_out;

  // workspace layout (floats)
  float* w = (float*)d_ws;
  float* V0 = w;   w += (size_t)4 * 4096 * 512;  // RA rows 0..7; SA/SB stages
  float* VD = w;   w += (size_t)4 * 4094 * 512;  // aliased as UsT
  float* DD = w;   w += (size_t)4 * 4094 * 512;  // aliased as UdT; late: Cb
  float* RB = w;   w += (size_t)4 * 4096 * 512;  // early: Xb; mid: fdft-Scr, Part; late: recon out
  float* XDre = w; w += XPLANE;
  float* XDim = w; w += XPLANE;
  float* XVre = w; w += XPLANE;
  float* XVim = w; w += XPLANE;
  float* UdFc = w; w += 2 * XPLANE;  // interleaved [row][i][re|im]; early: Wb0/Wb1 bf16
  float* UsFc = w; w += 2 * XPLANE;
  float* WT = w;
  float* RA = V0;
  float* SA = V0 + 4096;            // 4*16*512 = 32768 floats
  float* SB = V0 + 4096 + 32768;    // 4*256*512 = 524288 floats
  float* UdT = DD;
  float* UsT = VD;
  float* Part = RB;                 // 16*XPLANE = 5.77M <= 8.39M
  float* Scr  = RB;                 // fdft partials: 496*16384 = 8.13M <= 8.39M

  unsigned short* Xb  = (unsigned short*)RB;
  unsigned short* Cb  = (unsigned short*)DD;
  unsigned short* Wb0 = (unsigned short*)UdFc;
  unsigned short* Wb1 = (unsigned short*)UdFc;

  const size_t BASE_FLOATS = 36421632ull;
  const size_t WT_FLOATS   = 25165824ull;
  if (ws_size < BASE_FLOATS * 4) return;
  const bool use_wt = ws_size >= (BASE_FLOATS + WT_FLOATS) * 4;
  uint32* W4lo = (uint32*)WT;                       // 16*262144 u32 = 4194304 floats
  uint32* W4hi = (uint32*)(WT + 4194304ull);
  uint32* W2b  = (uint32*)(WT + 8388608ull);
  unsigned short* AudP = (unsigned short*)(WT + 12582912ull);
  unsigned short* AusP = (unsigned short*)(WT + 13369344ull);

  // 1. bf16 converts + Lk0 GEMM (MFMA)
  k_cvt_x<<<dim3(4096), dim3(256), 0, stream>>>(x, Xb);
  k_cvt_gen<<<dim3(128), dim3(256), 0, stream>>>(Lk0_w, Wb0);
  k_gemm_bf16<<<dim3(128, 4), dim3(256), 0, stream>>>(Xb, Wb0, Lk0_b, V0);

  // 2. fused decomposition: levels 1-4, 5-8, 9-11
  k_decomp_tree<<<dim3(256, 4), dim3(256), 0, stream>>>(
      V0, ec_s, ec_d, DD, VD, 1, 4, 4096);
  k_decomp_tree<<<dim3(16, 4), dim3(256), 0, stream>>>(
      VD + 4ull * 3584 * 512, ec_s, ec_d, DD, VD, 5, 4, 256);
  // level-8 v arena base = 4*(4096 - (4096>>7)) = 4*4064
  k_decomp_tree<<<dim3(1, 4), dim3(256), 0, stream>>>(
      VD + 4ull * 4064 * 512, ec_s, ec_d, DD, VD, 9, 3, 16);

  // 3. T0 on v_11
  k_t0<<<dim3(2), dim3(256), 0, stream>>>(VD + (size_t)4 * 4092 * 512, T0_w, T0_b, RA);

  // 4. weight repack to planar bf16 [f][g]; 1 (re,im) float4 pair/thread
  if (use_wt)
    k_transw6b<<<dim3(4096, 3), dim3(256), 0, stream>>>(
        Ar, Ai, Br, Bi, Cr, Ci, W4lo, W4hi, W2b);

  // 5. forward DFTs (chunk=64, 4-deep pipeline) -> partials, then
  //    deterministic reduction (no atomics anywhere -> replay-stable)
  k_fdft<<<dim3(68, 4, 2), dim3(256), 0, stream>>>(
      DD, VD, Scr, XDre, XDim, XVre, XVim);
  k_fdft_red<<<dim3(2560), dim3(256), 0, stream>>>(
      Scr, XDre, XDim, XVre, XVim);

  if (use_wt) {
    k_packA<<<dim3(384), dim3(256), 0, stream>>>(XDre, XDim, XVre, XVim, AudP, AusP);
    k_mixmm<<<dim3(16, 4, 4), dim3(256), 0, stream>>>(
        W4lo, W4hi, W2b, AudP, AusP, Part);
    k_reduce4<<<dim3((XPLANE + 255) / 256), dim3(256), 0, stream>>>(
        Part, UdFc, UsFc);
  } else {
    k_mix_fb<<<dim3(16, 4), dim3(512), 0, stream>>>(
        XDre, XDim, XVre, XVim, Ar, Ai, Br, Bi, Cr, Ci,
        UdFc, UsFc);
  }

  // 8. inverse DFTs into time-domain Ud/Us arenas
  k_idft<<<dim3(513, 4), dim3(256), 0, stream>>>(UdFc, UsFc, UdT, UsT);

  // 9. fused reconstruction: j=11..9 (RA->SA), j=8..5 (SA->SB), j=4..1 (SB->RB)
  k_recon_tree<<<dim3(1, 4), dim3(256), 0, stream>>>(
      RA, UdT, UsT, rc_e, rc_o, SA, 11, 3, 2, 2, 16);
  k_recon_tree<<<dim3(16, 4), dim3(256), 0, stream>>>(
      SA, UdT, UsT, rc_e, rc_o, SB, 8, 4, 1, 16, 256);
  k_recon_tree<<<dim3(256, 4), dim3(256), 0, stream>>>(
      SB, UdT, UsT, rc_e, rc_o, RB, 4, 4, 1, 256, 4096);

  // 10. Lk1 GEMM (MFMA)
  k_cvt_c<<<dim3(3072), dim3(256), 0, stream>>>(RB, Cb);
  k_cvt_gen<<<dim3(128), dim3(256), 0, stream>>>(Lk1_w, Wb1);
  k_gemm_bf16<<<dim3(96, 4), dim3(256), 0, stream>>>(Cb, Wb1, Lk1_b, out);
}